// Round 1
// baseline (13372.844 us; speedup 1.0000x reference)
//
#include <hip/hip_runtime.h>
#include <cstddef>

#define S_LEN 2048
#define XLEN_C 1024
#define DMODEL 512
#define NHEAD 16
#define HDIM 32
#define FFDIM 2048
#define NLAYER 24
#define TD3 1536

// ---------------------------------------------------------------------------
// GEMM (NT): C[M,N] = A[M,K] @ B[N,K]^T + bias[N], optional ReLU.
// M = 2048 fixed by grid. 64x64 tile, BK=16, 256 threads, 4x4 microtile.
// ---------------------------------------------------------------------------
template<bool RELU>
__global__ __launch_bounds__(256) void gemm_nt(const float* __restrict__ A,
                                               const float* __restrict__ B,
                                               const float* __restrict__ bias,
                                               float* __restrict__ C,
                                               int N, int K) {
  __shared__ float As[16][64];
  __shared__ float Bs[16][64];
  const int tid = threadIdx.x;
  const int tx = tid & 15, ty = tid >> 4;
  const int m0 = blockIdx.y << 6, n0 = blockIdx.x << 6;
  const int la = tid >> 2;          // tile row 0..63
  const int lc = (tid & 3) << 2;    // k offset 0,4,8,12
  const float* Ap = A + (size_t)(m0 + la) * K + lc;
  const float* Bp = B + (size_t)(n0 + la) * K + lc;
  float acc[4][4] = {};
  for (int k0 = 0; k0 < K; k0 += 16) {
    float4 av = *(const float4*)(Ap + k0);
    float4 bv = *(const float4*)(Bp + k0);
    __syncthreads();
    As[lc+0][la] = av.x; As[lc+1][la] = av.y; As[lc+2][la] = av.z; As[lc+3][la] = av.w;
    Bs[lc+0][la] = bv.x; Bs[lc+1][la] = bv.y; Bs[lc+2][la] = bv.z; Bs[lc+3][la] = bv.w;
    __syncthreads();
    #pragma unroll
    for (int k = 0; k < 16; ++k) {
      const float4 a4 = *(const float4*)&As[k][ty << 2];
      const float4 b4 = *(const float4*)&Bs[k][tx << 2];
      const float ar[4] = {a4.x, a4.y, a4.z, a4.w};
      const float br[4] = {b4.x, b4.y, b4.z, b4.w};
      #pragma unroll
      for (int i = 0; i < 4; ++i)
        #pragma unroll
        for (int j = 0; j < 4; ++j)
          acc[i][j] += ar[i] * br[j];
    }
  }
  const float4 bq = *(const float4*)&bias[n0 + (tx << 2)];
  const float bb[4] = {bq.x, bq.y, bq.z, bq.w};
  #pragma unroll
  for (int i = 0; i < 4; ++i) {
    float v0 = acc[i][0] + bb[0];
    float v1 = acc[i][1] + bb[1];
    float v2 = acc[i][2] + bb[2];
    float v3 = acc[i][3] + bb[3];
    if (RELU) {
      v0 = fmaxf(v0, 0.f); v1 = fmaxf(v1, 0.f);
      v2 = fmaxf(v2, 0.f); v3 = fmaxf(v3, 0.f);
    }
    float4 o; o.x = v0; o.y = v1; o.z = v2; o.w = v3;
    *(float4*)&C[(size_t)(m0 + (ty << 2) + i) * N + n0 + (tx << 2)] = o;
  }
}

// ---------------------------------------------------------------------------
// Flash-style attention. Block = (one head, 32 query rows), 256 threads.
// Thread layout: row = tid/8, col-group cg = tid%8; thread owns cols
// {cg + 8*j} of each 64-wide K tile (strided so Ks/Vs float4 reads hit 8
// distinct bank groups with the 36-float padded stride).
// Mask: text rows (q < 1024) attend cols [0,1024); audio rows attend
// cols [0, q]. exp(-1e5) == 0 in fp32, so hard masking matches reference.
// ---------------------------------------------------------------------------
__global__ __launch_bounds__(256) void attn_flash(const float* __restrict__ qkv,
                                                  float* __restrict__ out) {
  const int hh  = blockIdx.y;
  const int q0  = blockIdx.x << 5;
  const int tid = threadIdx.x;
  const int row = tid >> 3;
  const int cg  = tid & 7;
  const int q   = q0 + row;
  constexpr float SCALE = 0.17677669529663687f;  // 1/sqrt(32)

  __shared__ float Ks[64][36];
  __shared__ float Vs[64][36];

  // Q row into registers (8 redundant lanes per row -> L1 broadcast).
  float4 qv[8];
  #pragma unroll
  for (int i = 0; i < 8; ++i)
    qv[i] = *(const float4*)&qkv[(size_t)q * TD3 + hh * HDIM + (i << 2)];

  float m = -3.0e38f, l = 0.f;
  float acc[32];
  #pragma unroll
  for (int d = 0; d < 32; ++d) acc[d] = 0.f;

  const int kend   = (q0 < XLEN_C) ? XLEN_C : (q0 + 32);
  const int ntiles = (kend + 63) >> 6;

  for (int t = 0; t < ntiles; ++t) {
    const int c0 = t << 6;
    __syncthreads();
    #pragma unroll
    for (int i = 0; i < 2; ++i) {
      const int chunk = tid + (i << 8);
      const int r  = chunk >> 3;
      const int c4 = (chunk & 7) << 2;
      *(float4*)&Ks[r][c4] =
          *(const float4*)&qkv[(size_t)(c0 + r) * TD3 + DMODEL + hh * HDIM + c4];
      *(float4*)&Vs[r][c4] =
          *(const float4*)&qkv[(size_t)(c0 + r) * TD3 + 2 * DMODEL + hh * HDIM + c4];
    }
    __syncthreads();

    // scores for this thread's 8 columns
    float s[8];
    #pragma unroll
    for (int j = 0; j < 8; ++j) s[j] = 0.f;
    #pragma unroll
    for (int dd = 0; dd < 8; ++dd) {
      const float4 q4 = qv[dd];
      #pragma unroll
      for (int j = 0; j < 8; ++j) {
        const float4 k4 = *(const float4*)&Ks[cg + (j << 3)][dd << 2];
        s[j] += q4.x * k4.x + q4.y * k4.y + q4.z * k4.z + q4.w * k4.w;
      }
    }
    float tmax = -3.0e38f;
    #pragma unroll
    for (int j = 0; j < 8; ++j) {
      const int c = c0 + cg + (j << 3);
      const bool ok = (c < XLEN_C) | (c <= q);
      s[j] = ok ? s[j] * SCALE : -3.0e38f;
      tmax = fmaxf(tmax, s[j]);
    }
    tmax = fmaxf(tmax, __shfl_xor(tmax, 1));
    tmax = fmaxf(tmax, __shfl_xor(tmax, 2));
    tmax = fmaxf(tmax, __shfl_xor(tmax, 4));
    const float mnew  = fmaxf(m, tmax);
    const float alpha = __expf(m - mnew);
    m = mnew;
    float p[8]; float psum = 0.f;
    #pragma unroll
    for (int j = 0; j < 8; ++j) { p[j] = __expf(s[j] - mnew); psum += p[j]; }
    l = l * alpha + psum;
    #pragma unroll
    for (int d = 0; d < 32; ++d) acc[d] *= alpha;
    #pragma unroll
    for (int j = 0; j < 8; ++j) {
      const float pj = p[j];
      const int c = cg + (j << 3);
      #pragma unroll
      for (int dd = 0; dd < 8; ++dd) {
        const float4 v4 = *(const float4*)&Vs[c][dd << 2];
        acc[(dd << 2) + 0] += pj * v4.x;
        acc[(dd << 2) + 1] += pj * v4.y;
        acc[(dd << 2) + 2] += pj * v4.z;
        acc[(dd << 2) + 3] += pj * v4.w;
      }
    }
  }

  // reduce partials across the 8 col-groups of each row
  l += __shfl_xor(l, 1); l += __shfl_xor(l, 2); l += __shfl_xor(l, 4);
  #pragma unroll
  for (int d = 0; d < 32; ++d) {
    acc[d] += __shfl_xor(acc[d], 1);
    acc[d] += __shfl_xor(acc[d], 2);
    acc[d] += __shfl_xor(acc[d], 4);
  }
  const float inv = 1.f / l;
  // static-index extraction of this thread's 4-dim slice (avoid scratch spill)
  float o0 = 0.f, o1 = 0.f, o2 = 0.f, o3 = 0.f;
  #pragma unroll
  for (int g = 0; g < 8; ++g)
    if (cg == g) { o0 = acc[g*4+0]; o1 = acc[g*4+1]; o2 = acc[g*4+2]; o3 = acc[g*4+3]; }
  float4 o4; o4.x = o0*inv; o4.y = o1*inv; o4.z = o2*inv; o4.w = o3*inv;
  *(float4*)&out[(size_t)q * DMODEL + hh * HDIM + (cg << 2)] = o4;
}

// ---------------------------------------------------------------------------
// Fused residual add + LayerNorm over D=512. One block per row, 256 threads.
// ---------------------------------------------------------------------------
__global__ __launch_bounds__(256) void add_layernorm(const float* __restrict__ h,
                                                     const float* __restrict__ r,
                                                     const float* __restrict__ w,
                                                     const float* __restrict__ b,
                                                     float* __restrict__ out) {
  const int row = blockIdx.x;
  const int tid = threadIdx.x;
  const float2 hv = *(const float2*)&h[(size_t)row * DMODEL + tid * 2];
  const float2 rv = *(const float2*)&r[(size_t)row * DMODEL + tid * 2];
  const float a0 = hv.x + rv.x, a1 = hv.y + rv.y;
  float s = a0 + a1, ss = a0 * a0 + a1 * a1;
  #pragma unroll
  for (int off = 32; off; off >>= 1) {
    s  += __shfl_xor(s, off);
    ss += __shfl_xor(ss, off);
  }
  __shared__ float sb[4], ssb[4];
  const int wid = tid >> 6;
  if ((tid & 63) == 0) { sb[wid] = s; ssb[wid] = ss; }
  __syncthreads();
  s  = sb[0] + sb[1] + sb[2] + sb[3];
  ss = ssb[0] + ssb[1] + ssb[2] + ssb[3];
  const float mean = s * (1.f / DMODEL);
  const float var  = ss * (1.f / DMODEL) - mean * mean;
  const float rs   = rsqrtf(var + 1e-5f);
  const float2 wv = *(const float2*)&w[tid * 2];
  const float2 bv = *(const float2*)&b[tid * 2];
  float2 o;
  o.x = (a0 - mean) * rs * wv.x + bv.x;
  o.y = (a1 - mean) * rs * wv.y + bv.y;
  *(float2*)&out[(size_t)row * DMODEL + tid * 2] = o;
}

// ---------------------------------------------------------------------------
extern "C" void kernel_launch(void* const* d_in, const int* in_sizes, int n_in,
                              void* d_out, int out_size, void* d_ws, size_t ws_size,
                              hipStream_t stream) {
  const float* x     = (const float*)d_in[0];
  const float* qkv_w = (const float*)d_in[1];
  const float* qkv_b = (const float*)d_in[2];
  const float* out_w = (const float*)d_in[3];
  const float* out_b = (const float*)d_in[4];
  const float* w1    = (const float*)d_in[5];
  const float* b1    = (const float*)d_in[6];
  const float* w2    = (const float*)d_in[7];
  const float* b2    = (const float*)d_in[8];
  const float* nw1   = (const float*)d_in[9];
  const float* nb1   = (const float*)d_in[10];
  const float* nw2   = (const float*)d_in[11];
  const float* nb2   = (const float*)d_in[12];

  // workspace layout (floats): ~42 MB total
  float* Hc  = (float*)d_ws;                       // [S, D]
  float* qkv = Hc  + (size_t)S_LEN * DMODEL;       // [S, 3D]
  float* oat = qkv + (size_t)S_LEN * TD3;          // [S, D]
  float* opr = oat + (size_t)S_LEN * DMODEL;       // [S, D]
  float* mid = opr + (size_t)S_LEN * DMODEL;       // [S, FF]

  hipMemcpyAsync(Hc, x, sizeof(float) * S_LEN * DMODEL,
                 hipMemcpyDeviceToDevice, stream);

  for (int l = 0; l < NLAYER; ++l) {
    const float* qw = qkv_w + (size_t)l * TD3 * DMODEL;
    const float* qb = qkv_b + (size_t)l * TD3;
    const float* ow = out_w + (size_t)l * DMODEL * DMODEL;
    const float* ob = out_b + (size_t)l * DMODEL;
    const float* W1 = w1 + (size_t)l * FFDIM * DMODEL;
    const float* B1 = b1 + (size_t)l * FFDIM;
    const float* W2 = w2 + (size_t)l * DMODEL * FFDIM;
    const float* B2 = b2 + (size_t)l * DMODEL;

    gemm_nt<false><<<dim3(TD3 / 64, S_LEN / 64), 256, 0, stream>>>(
        Hc, qw, qb, qkv, TD3, DMODEL);
    attn_flash<<<dim3(S_LEN / 32, NHEAD), 256, 0, stream>>>(qkv, oat);
    gemm_nt<false><<<dim3(DMODEL / 64, S_LEN / 64), 256, 0, stream>>>(
        oat, ow, ob, opr, DMODEL, DMODEL);
    add_layernorm<<<S_LEN, 256, 0, stream>>>(
        Hc, opr, nw1 + (size_t)l * DMODEL, nb1 + (size_t)l * DMODEL, Hc);
    gemm_nt<true><<<dim3(FFDIM / 64, S_LEN / 64), 256, 0, stream>>>(
        Hc, W1, B1, mid, FFDIM, DMODEL);
    gemm_nt<false><<<dim3(DMODEL / 64, S_LEN / 64), 256, 0, stream>>>(
        mid, W2, B2, opr, DMODEL, FFDIM);
    add_layernorm<<<S_LEN, 256, 0, stream>>>(
        Hc, opr, nw2 + (size_t)l * DMODEL, nb2 + (size_t)l * DMODEL, Hc);
  }

  hipMemcpyAsync(d_out, Hc, sizeof(float) * S_LEN * DMODEL,
                 hipMemcpyDeviceToDevice, stream);
}

// Round 2
// 9289.751 us; speedup vs baseline: 1.4395x; 1.4395x over previous
//
#include <hip/hip_runtime.h>
#include <cstddef>

#define S_LEN 2048
#define XLEN_C 1024
#define DMODEL 512
#define NHEAD 16
#define HDIM 32
#define FFDIM 2048
#define NLAYER 24
#define TD3 1536

typedef __attribute__((ext_vector_type(4))) float f32x4;
typedef __attribute__((ext_vector_type(8))) short short8;

// Split fp32 -> bf16 hi + bf16 lo (both RNE). x ~= hi + lo, err ~ 2^-17 rel.
__device__ __forceinline__ void split2(float x, unsigned short& h, unsigned short& l) {
  unsigned u = __float_as_uint(x);
  unsigned r = u + 0x7FFFu + ((u >> 16) & 1u);
  h = (unsigned short)(r >> 16);
  float hf = __uint_as_float((unsigned)h << 16);
  float lo = x - hf;                       // exact (Sterbenz)
  unsigned u2 = __float_as_uint(lo);
  unsigned r2 = u2 + 0x7FFFu + ((u2 >> 16) & 1u);
  l = (unsigned short)(r2 >> 16);
}

// ---------------------------------------------------------------------------
// Split-bf16 MFMA GEMM (NT): C[M,N] = A[M,K] @ B[N,K]^T + bias[N], opt ReLU.
// fp32-grade accuracy via 3-product emulation: AhBh + AhBl + AlBh.
// BM=128, BN=64, BK=32. 256 threads = 4 waves in 2x2; wave tile 64x32 =
// 4x2 frags of 16x16. LDS rows padded to 40 bf16 (80B stride): bank access
// per ds_read_b128 is perfectly balanced (8 word-accesses per bank).
// ---------------------------------------------------------------------------
template<bool RELU>
__global__ __launch_bounds__(256) void gemm_mfma(const float* __restrict__ A,
                                                 const float* __restrict__ B,
                                                 const float* __restrict__ bias,
                                                 float* __restrict__ C,
                                                 int N, int K) {
  __shared__ __align__(16) unsigned short Ah[128][40];
  __shared__ __align__(16) unsigned short Al[128][40];
  __shared__ __align__(16) unsigned short Bh[64][40];
  __shared__ __align__(16) unsigned short Bl[64][40];

  const int tid  = threadIdx.x;
  const int m0   = blockIdx.y << 7;
  const int n0   = blockIdx.x << 6;
  const int w    = tid >> 6;
  const int lane = tid & 63;
  const int wm   = (w >> 1) << 6;   // 0 or 64
  const int wn   = (w & 1) << 5;    // 0 or 32
  const int fr   = lane & 15;       // row (A) / col (B) within frag
  const int fq   = lane >> 4;       // k-chunk 0..3 (8 bf16 each)

  // staging assignments
  const int ar = tid >> 1, ac = (tid & 1) << 4;   // A: 16 floats per thread
  const int br = tid >> 2, bc = (tid & 3) << 3;   // B: 8 floats per thread
  const float* Ap = A + (size_t)(m0 + ar) * K + ac;
  const float* Bp = B + (size_t)(n0 + br) * K + bc;

  f32x4 acc[4][2];
  #pragma unroll
  for (int i = 0; i < 4; ++i)
    #pragma unroll
    for (int j = 0; j < 2; ++j)
      acc[i][j] = (f32x4){0.f, 0.f, 0.f, 0.f};

  for (int k0 = 0; k0 < K; k0 += 32) {
    // ---- global loads + split (overlaps prior iter's tail) ----
    float4 av0 = *(const float4*)(Ap + k0 + 0);
    float4 av1 = *(const float4*)(Ap + k0 + 4);
    float4 av2 = *(const float4*)(Ap + k0 + 8);
    float4 av3 = *(const float4*)(Ap + k0 + 12);
    float4 bv0 = *(const float4*)(Bp + k0 + 0);
    float4 bv1 = *(const float4*)(Bp + k0 + 4);
    unsigned short ah16[16], al16[16], bh8[8], bl8[8];
    {
      const float af[16] = {av0.x, av0.y, av0.z, av0.w, av1.x, av1.y, av1.z, av1.w,
                            av2.x, av2.y, av2.z, av2.w, av3.x, av3.y, av3.z, av3.w};
      #pragma unroll
      for (int i = 0; i < 16; ++i) split2(af[i], ah16[i], al16[i]);
      const float bf[8] = {bv0.x, bv0.y, bv0.z, bv0.w, bv1.x, bv1.y, bv1.z, bv1.w};
      #pragma unroll
      for (int i = 0; i < 8; ++i) split2(bf[i], bh8[i], bl8[i]);
    }
    __syncthreads();   // previous iteration's frag reads complete
    *(short8*)&Ah[ar][ac + 0] = *(short8*)&ah16[0];
    *(short8*)&Ah[ar][ac + 8] = *(short8*)&ah16[8];
    *(short8*)&Al[ar][ac + 0] = *(short8*)&al16[0];
    *(short8*)&Al[ar][ac + 8] = *(short8*)&al16[8];
    *(short8*)&Bh[br][bc] = *(short8*)&bh8[0];
    *(short8*)&Bl[br][bc] = *(short8*)&bl8[0];
    __syncthreads();

    // ---- fragments ----
    short8 fah[4], fal[4], fbh[2], fbl[2];
    #pragma unroll
    for (int fm = 0; fm < 4; ++fm) {
      fah[fm] = *(const short8*)&Ah[wm + (fm << 4) + fr][fq << 3];
      fal[fm] = *(const short8*)&Al[wm + (fm << 4) + fr][fq << 3];
    }
    #pragma unroll
    for (int fn = 0; fn < 2; ++fn) {
      fbh[fn] = *(const short8*)&Bh[wn + (fn << 4) + fr][fq << 3];
      fbl[fn] = *(const short8*)&Bl[wn + (fn << 4) + fr][fq << 3];
    }
    // ---- 3-product split MFMA ----
    #pragma unroll
    for (int fm = 0; fm < 4; ++fm)
      #pragma unroll
      for (int fn = 0; fn < 2; ++fn) {
        acc[fm][fn] = __builtin_amdgcn_mfma_f32_16x16x32_bf16(fah[fm], fbh[fn], acc[fm][fn], 0, 0, 0);
        acc[fm][fn] = __builtin_amdgcn_mfma_f32_16x16x32_bf16(fah[fm], fbl[fn], acc[fm][fn], 0, 0, 0);
        acc[fm][fn] = __builtin_amdgcn_mfma_f32_16x16x32_bf16(fal[fm], fbh[fn], acc[fm][fn], 0, 0, 0);
      }
  }

  // ---- epilogue: C/D layout col=lane&15, row=(lane>>4)*4+i ----
  #pragma unroll
  for (int fn = 0; fn < 2; ++fn) {
    const int col = n0 + wn + (fn << 4) + fr;
    const float bb = bias[col];
    #pragma unroll
    for (int fm = 0; fm < 4; ++fm) {
      const int rbase = m0 + wm + (fm << 4) + (fq << 2);
      #pragma unroll
      for (int i = 0; i < 4; ++i) {
        float v = acc[fm][fn][i] + bb;
        if (RELU) v = fmaxf(v, 0.f);
        C[(size_t)(rbase + i) * N + col] = v;
      }
    }
  }
}

// ---------------------------------------------------------------------------
// Flash-style attention (fp32). Block = (one head, 32 query rows), 256 thr.
// Grid is (head, qtile) with head FAST so consecutive blocks differ in head
// and a CU's resident blocks span distant qtiles -> balanced work.
// ---------------------------------------------------------------------------
__global__ __launch_bounds__(256) void attn_flash(const float* __restrict__ qkv,
                                                  float* __restrict__ out) {
  const int hh  = blockIdx.x;
  const int q0  = blockIdx.y << 5;
  const int tid = threadIdx.x;
  const int row = tid >> 3;
  const int cg  = tid & 7;
  const int q   = q0 + row;
  constexpr float SCALE = 0.17677669529663687f;  // 1/sqrt(32)

  __shared__ float Ks[64][36];
  __shared__ float Vs[64][36];

  float4 qv[8];
  #pragma unroll
  for (int i = 0; i < 8; ++i)
    qv[i] = *(const float4*)&qkv[(size_t)q * TD3 + hh * HDIM + (i << 2)];

  float m = -3.0e38f, l = 0.f;
  float acc[32];
  #pragma unroll
  for (int d = 0; d < 32; ++d) acc[d] = 0.f;

  const int kend   = (q0 < XLEN_C) ? XLEN_C : (q0 + 32);
  const int ntiles = (kend + 63) >> 6;

  for (int t = 0; t < ntiles; ++t) {
    const int c0 = t << 6;
    __syncthreads();
    #pragma unroll
    for (int i = 0; i < 2; ++i) {
      const int chunk = tid + (i << 8);
      const int r  = chunk >> 3;
      const int c4 = (chunk & 7) << 2;
      *(float4*)&Ks[r][c4] =
          *(const float4*)&qkv[(size_t)(c0 + r) * TD3 + DMODEL + hh * HDIM + c4];
      *(float4*)&Vs[r][c4] =
          *(const float4*)&qkv[(size_t)(c0 + r) * TD3 + 2 * DMODEL + hh * HDIM + c4];
    }
    __syncthreads();

    float s[8];
    #pragma unroll
    for (int j = 0; j < 8; ++j) s[j] = 0.f;
    #pragma unroll
    for (int dd = 0; dd < 8; ++dd) {
      const float4 q4 = qv[dd];
      #pragma unroll
      for (int j = 0; j < 8; ++j) {
        const float4 k4 = *(const float4*)&Ks[cg + (j << 3)][dd << 2];
        s[j] += q4.x * k4.x + q4.y * k4.y + q4.z * k4.z + q4.w * k4.w;
      }
    }
    float tmax = -3.0e38f;
    #pragma unroll
    for (int j = 0; j < 8; ++j) {
      const int c = c0 + cg + (j << 3);
      const bool ok = (c < XLEN_C) | (c <= q);
      s[j] = ok ? s[j] * SCALE : -3.0e38f;
      tmax = fmaxf(tmax, s[j]);
    }
    tmax = fmaxf(tmax, __shfl_xor(tmax, 1));
    tmax = fmaxf(tmax, __shfl_xor(tmax, 2));
    tmax = fmaxf(tmax, __shfl_xor(tmax, 4));
    const float mnew  = fmaxf(m, tmax);
    const float alpha = __expf(m - mnew);
    m = mnew;
    float p[8]; float psum = 0.f;
    #pragma unroll
    for (int j = 0; j < 8; ++j) { p[j] = __expf(s[j] - mnew); psum += p[j]; }
    l = l * alpha + psum;
    #pragma unroll
    for (int d = 0; d < 32; ++d) acc[d] *= alpha;
    #pragma unroll
    for (int j = 0; j < 8; ++j) {
      const float pj = p[j];
      const int c = cg + (j << 3);
      #pragma unroll
      for (int dd = 0; dd < 8; ++dd) {
        const float4 v4 = *(const float4*)&Vs[c][dd << 2];
        acc[(dd << 2) + 0] += pj * v4.x;
        acc[(dd << 2) + 1] += pj * v4.y;
        acc[(dd << 2) + 2] += pj * v4.z;
        acc[(dd << 2) + 3] += pj * v4.w;
      }
    }
  }

  l += __shfl_xor(l, 1); l += __shfl_xor(l, 2); l += __shfl_xor(l, 4);
  #pragma unroll
  for (int d = 0; d < 32; ++d) {
    acc[d] += __shfl_xor(acc[d], 1);
    acc[d] += __shfl_xor(acc[d], 2);
    acc[d] += __shfl_xor(acc[d], 4);
  }
  const float inv = 1.f / l;
  float o0 = 0.f, o1 = 0.f, o2 = 0.f, o3 = 0.f;
  #pragma unroll
  for (int g = 0; g < 8; ++g)
    if (cg == g) { o0 = acc[g*4+0]; o1 = acc[g*4+1]; o2 = acc[g*4+2]; o3 = acc[g*4+3]; }
  float4 o4; o4.x = o0*inv; o4.y = o1*inv; o4.z = o2*inv; o4.w = o3*inv;
  *(float4*)&out[(size_t)q * DMODEL + hh * HDIM + (cg << 2)] = o4;
}

// ---------------------------------------------------------------------------
// Fused residual add + LayerNorm over D=512. One block per row, 256 threads.
// ---------------------------------------------------------------------------
__global__ __launch_bounds__(256) void add_layernorm(const float* __restrict__ h,
                                                     const float* __restrict__ r,
                                                     const float* __restrict__ w,
                                                     const float* __restrict__ b,
                                                     float* __restrict__ out) {
  const int row = blockIdx.x;
  const int tid = threadIdx.x;
  const float2 hv = *(const float2*)&h[(size_t)row * DMODEL + tid * 2];
  const float2 rv = *(const float2*)&r[(size_t)row * DMODEL + tid * 2];
  const float a0 = hv.x + rv.x, a1 = hv.y + rv.y;
  float s = a0 + a1, ss = a0 * a0 + a1 * a1;
  #pragma unroll
  for (int off = 32; off; off >>= 1) {
    s  += __shfl_xor(s, off);
    ss += __shfl_xor(ss, off);
  }
  __shared__ float sb[4], ssb[4];
  const int wid = tid >> 6;
  if ((tid & 63) == 0) { sb[wid] = s; ssb[wid] = ss; }
  __syncthreads();
  s  = sb[0] + sb[1] + sb[2] + sb[3];
  ss = ssb[0] + ssb[1] + ssb[2] + ssb[3];
  const float mean = s * (1.f / DMODEL);
  const float var  = ss * (1.f / DMODEL) - mean * mean;
  const float rs   = rsqrtf(var + 1e-5f);
  const float2 wv = *(const float2*)&w[tid * 2];
  const float2 bv = *(const float2*)&b[tid * 2];
  float2 o;
  o.x = (a0 - mean) * rs * wv.x + bv.x;
  o.y = (a1 - mean) * rs * wv.y + bv.y;
  *(float2*)&out[(size_t)row * DMODEL + tid * 2] = o;
}

// ---------------------------------------------------------------------------
extern "C" void kernel_launch(void* const* d_in, const int* in_sizes, int n_in,
                              void* d_out, int out_size, void* d_ws, size_t ws_size,
                              hipStream_t stream) {
  const float* x     = (const float*)d_in[0];
  const float* qkv_w = (const float*)d_in[1];
  const float* qkv_b = (const float*)d_in[2];
  const float* out_w = (const float*)d_in[3];
  const float* out_b = (const float*)d_in[4];
  const float* w1    = (const float*)d_in[5];
  const float* b1    = (const float*)d_in[6];
  const float* w2    = (const float*)d_in[7];
  const float* b2    = (const float*)d_in[8];
  const float* nw1   = (const float*)d_in[9];
  const float* nb1   = (const float*)d_in[10];
  const float* nw2   = (const float*)d_in[11];
  const float* nb2   = (const float*)d_in[12];

  float* Hc  = (float*)d_ws;                       // [S, D]
  float* qkv = Hc  + (size_t)S_LEN * DMODEL;       // [S, 3D]
  float* oat = qkv + (size_t)S_LEN * TD3;          // [S, D]
  float* opr = oat + (size_t)S_LEN * DMODEL;       // [S, D]
  float* mid = opr + (size_t)S_LEN * DMODEL;       // [S, FF]

  hipMemcpyAsync(Hc, x, sizeof(float) * S_LEN * DMODEL,
                 hipMemcpyDeviceToDevice, stream);

  for (int l = 0; l < NLAYER; ++l) {
    const float* qw = qkv_w + (size_t)l * TD3 * DMODEL;
    const float* qb = qkv_b + (size_t)l * TD3;
    const float* ow = out_w + (size_t)l * DMODEL * DMODEL;
    const float* ob = out_b + (size_t)l * DMODEL;
    const float* W1 = w1 + (size_t)l * FFDIM * DMODEL;
    const float* B1 = b1 + (size_t)l * FFDIM;
    const float* W2 = w2 + (size_t)l * DMODEL * FFDIM;
    const float* B2 = b2 + (size_t)l * DMODEL;

    gemm_mfma<false><<<dim3(TD3 / 64, S_LEN / 128), 256, 0, stream>>>(
        Hc, qw, qb, qkv, TD3, DMODEL);
    attn_flash<<<dim3(NHEAD, S_LEN / 32), 256, 0, stream>>>(qkv, oat);
    gemm_mfma<false><<<dim3(DMODEL / 64, S_LEN / 128), 256, 0, stream>>>(
        oat, ow, ob, opr, DMODEL, DMODEL);
    add_layernorm<<<S_LEN, 256, 0, stream>>>(
        Hc, opr, nw1 + (size_t)l * DMODEL, nb1 + (size_t)l * DMODEL, Hc);
    gemm_mfma<true><<<dim3(FFDIM / 64, S_LEN / 128), 256, 0, stream>>>(
        Hc, W1, B1, mid, FFDIM, DMODEL);
    gemm_mfma<false><<<dim3(DMODEL / 64, S_LEN / 128), 256, 0, stream>>>(
        mid, W2, B2, opr, DMODEL, FFDIM);
    add_layernorm<<<S_LEN, 256, 0, stream>>>(
        Hc, opr, nw2 + (size_t)l * DMODEL, nb2 + (size_t)l * DMODEL, Hc);
  }

  hipMemcpyAsync(d_out, Hc, sizeof(float) * S_LEN * DMODEL,
                 hipMemcpyDeviceToDevice, stream);
}

// Round 5
// 5827.107 us; speedup vs baseline: 2.2949x; 1.5942x over previous
//
#include <hip/hip_runtime.h>
#include <cstddef>

#define S_LEN 2048
#define XLEN_C 1024
#define DMODEL 512
#define NHEAD 16
#define HDIM 32
#define FFDIM 2048
#define NLAYER 24
#define TD3 1536

typedef __attribute__((ext_vector_type(4))) float f32x4;
typedef __attribute__((ext_vector_type(8))) short short8;

// Split fp32 -> bf16 hi + bf16 lo (both RNE). x ~= hi + lo, err ~ 2^-17 rel.
__device__ __forceinline__ void split2(float x, unsigned short& h, unsigned short& l) {
  unsigned u = __float_as_uint(x);
  unsigned r = u + 0x7FFFu + ((u >> 16) & 1u);
  h = (unsigned short)(r >> 16);
  float hf = __uint_as_float((unsigned)h << 16);
  float lo = x - hf;                       // exact
  unsigned u2 = __float_as_uint(lo);
  unsigned r2 = u2 + 0x7FFFu + ((u2 >> 16) & 1u);
  l = (unsigned short)(r2 >> 16);
}

// ---------------------------------------------------------------------------
// MFMA GEMM, A pre-split bf16 pair, B fp32 weights split in-kernel.
// C[M,N] = A @ B^T + bias. BM=32*WMF (128 or 64), BN=64, BK=32.
// 256 threads = 4 waves (2 in M x 2 in N); wave tile (16*WMF) x 32.
// 3-product split MFMA: AhBh + AhBl + AlBh (fp32-grade).
// LDS rows padded to 40 shorts (80B): all b128 accesses bank-uniform.
// ---------------------------------------------------------------------------
template<int WMF, bool RELU, bool SPLIT_OUT>
__global__ __launch_bounds__(256) void gemm_mfma(const unsigned short* __restrict__ Ahg,
                                                 const unsigned short* __restrict__ Alg,
                                                 const float* __restrict__ Bg,
                                                 const float* __restrict__ bias,
                                                 float* __restrict__ Cf,
                                                 unsigned short* __restrict__ Ch,
                                                 unsigned short* __restrict__ Cl,
                                                 int N, int K) {
  constexpr int BM = 32 * WMF;
  __shared__ __align__(16) unsigned short Ahs[BM][40];
  __shared__ __align__(16) unsigned short Als[BM][40];
  __shared__ __align__(16) unsigned short Bhs[64][40];
  __shared__ __align__(16) unsigned short Bls[64][40];

  const int tid  = threadIdx.x;
  const int m0   = blockIdx.y * BM;
  const int n0   = blockIdx.x << 6;
  const int w    = tid >> 6;
  const int lane = tid & 63;
  const int wm   = (w >> 1) * (16 * WMF);
  const int wn   = (w & 1) << 5;
  const int fr   = lane & 15;
  const int fq   = lane >> 4;

  const int br = tid >> 2, bc = (tid & 3) << 3;

  f32x4 acc[WMF][2];
  #pragma unroll
  for (int i = 0; i < WMF; ++i)
    #pragma unroll
    for (int j = 0; j < 2; ++j)
      acc[i][j] = (f32x4){0.f, 0.f, 0.f, 0.f};

  for (int k0 = 0; k0 < K; k0 += 32) {
    // B split (weights, fp32 in)
    float4 b0 = *(const float4*)&Bg[(size_t)(n0 + br) * K + k0 + bc];
    float4 b1 = *(const float4*)&Bg[(size_t)(n0 + br) * K + k0 + bc + 4];
    short8 bh, bl;
    {
      const float bf[8] = {b0.x, b0.y, b0.z, b0.w, b1.x, b1.y, b1.z, b1.w};
      #pragma unroll
      for (int i = 0; i < 8; ++i) {
        unsigned short h, lo; split2(bf[i], h, lo);
        bh[i] = (short)h; bl[i] = (short)lo;
      }
    }
    // A pre-split loads
    short8 a_h[(BM * 4) / 256], a_l[(BM * 4) / 256];
    #pragma unroll
    for (int it = 0; it < (BM * 4) / 256; ++it) {
      const int c = tid + (it << 8);
      const int arow = c >> 2, acol = (c & 3) << 3;
      a_h[it] = *(const short8*)&Ahg[(size_t)(m0 + arow) * K + k0 + acol];
      a_l[it] = *(const short8*)&Alg[(size_t)(m0 + arow) * K + k0 + acol];
    }
    __syncthreads();
    #pragma unroll
    for (int it = 0; it < (BM * 4) / 256; ++it) {
      const int c = tid + (it << 8);
      const int arow = c >> 2, acol = (c & 3) << 3;
      *(short8*)&Ahs[arow][acol] = a_h[it];
      *(short8*)&Als[arow][acol] = a_l[it];
    }
    *(short8*)&Bhs[br][bc] = bh;
    *(short8*)&Bls[br][bc] = bl;
    __syncthreads();

    short8 fah[WMF], fal[WMF], fbh[2], fbl[2];
    #pragma unroll
    for (int fm = 0; fm < WMF; ++fm) {
      fah[fm] = *(const short8*)&Ahs[wm + (fm << 4) + fr][fq << 3];
      fal[fm] = *(const short8*)&Als[wm + (fm << 4) + fr][fq << 3];
    }
    #pragma unroll
    for (int fn = 0; fn < 2; ++fn) {
      fbh[fn] = *(const short8*)&Bhs[wn + (fn << 4) + fr][fq << 3];
      fbl[fn] = *(const short8*)&Bls[wn + (fn << 4) + fr][fq << 3];
    }
    #pragma unroll
    for (int fm = 0; fm < WMF; ++fm)
      #pragma unroll
      for (int fn = 0; fn < 2; ++fn) {
        acc[fm][fn] = __builtin_amdgcn_mfma_f32_16x16x32_bf16(fah[fm], fbh[fn], acc[fm][fn], 0, 0, 0);
        acc[fm][fn] = __builtin_amdgcn_mfma_f32_16x16x32_bf16(fah[fm], fbl[fn], acc[fm][fn], 0, 0, 0);
        acc[fm][fn] = __builtin_amdgcn_mfma_f32_16x16x32_bf16(fal[fm], fbh[fn], acc[fm][fn], 0, 0, 0);
      }
  }

  // epilogue: C/D layout col=lane&15, row=(lane>>4)*4+i
  #pragma unroll
  for (int fn = 0; fn < 2; ++fn) {
    const int col = n0 + wn + (fn << 4) + fr;
    const float bb = bias[col];
    #pragma unroll
    for (int fm = 0; fm < WMF; ++fm) {
      const int rbase = m0 + wm + (fm << 4) + (fq << 2);
      #pragma unroll
      for (int i = 0; i < 4; ++i) {
        float v = acc[fm][fn][i] + bb;
        if (RELU) v = fmaxf(v, 0.f);
        const size_t idx = (size_t)(rbase + i) * N + col;
        if (SPLIT_OUT) {
          unsigned short h, lo; split2(v, h, lo);
          Ch[idx] = h; Cl[idx] = lo;
        } else {
          Cf[idx] = v;
        }
      }
    }
  }
}

// ---------------------------------------------------------------------------
// MFMA flash attention, fp32-grade (3-product split on QK^T and PV).
// Block = (head, 64 q-rows), 4 waves x 16 rows. Swapped QK^T: S^T = K.Q^T
// so lane fr holds scores for q-row fr; row-reduce = 16 local + 2 shfl.
// V staged transposed ([32d][72k]) via column-segment writes; P goes
// through per-wave LDS to form the PV A-fragment.
// ---------------------------------------------------------------------------
__global__ __launch_bounds__(256) void attn_mfma(const unsigned short* __restrict__ qh_g,
                                                 const unsigned short* __restrict__ ql_g,
                                                 unsigned short* __restrict__ oh_g,
                                                 unsigned short* __restrict__ ol_g) {
  const int hh  = blockIdx.x;
  const int q0  = blockIdx.y << 6;
  const int tid = threadIdx.x;
  const int w   = tid >> 6;
  const int lane = tid & 63;
  const int fr = lane & 15;
  const int fq = lane >> 4;
  constexpr float SCALE = 0.17677669529663687f;  // 1/sqrt(32)

  __shared__ __align__(16) unsigned short Kh[64][40];
  __shared__ __align__(16) unsigned short Kl[64][40];
  __shared__ __align__(16) unsigned short Vth[32][72];
  __shared__ __align__(16) unsigned short Vtl[32][72];
  __shared__ __align__(16) unsigned short Ph[4][16][72];
  __shared__ __align__(16) unsigned short Pl[4][16][72];

  const int qrow = q0 + (w << 4) + fr;
  const short8 fQh = *(const short8*)&qh_g[(size_t)qrow * TD3 + hh * HDIM + (fq << 3)];
  const short8 fQl = *(const short8*)&ql_g[(size_t)qrow * TD3 + hh * HDIM + (fq << 3)];

  float m = -3.0e38f, l = 0.f;
  f32x4 accO[2];
  accO[0] = (f32x4){0.f, 0.f, 0.f, 0.f};
  accO[1] = (f32x4){0.f, 0.f, 0.f, 0.f};

  const int kend   = (q0 < XLEN_C) ? XLEN_C : (q0 + 64);
  const int ntiles = kend >> 6;

  const int krow = tid >> 2, kcol = (tid & 3) << 3;  // K staging
  const int vd = tid & 31, vseg = tid >> 5;          // V staging (transposed)

  for (int t = 0; t < ntiles; ++t) {
    const int c0 = t << 6;
    __syncthreads();
    // K: row-major pair staging
    *(short8*)&Kh[krow][kcol] =
        *(const short8*)&qh_g[(size_t)(c0 + krow) * TD3 + DMODEL + hh * HDIM + kcol];
    *(short8*)&Kl[krow][kcol] =
        *(const short8*)&ql_g[(size_t)(c0 + krow) * TD3 + DMODEL + hh * HDIM + kcol];
    // V: transposed staging, column segments (coalesced u16 loads, b128 writes)
    short8 vh8, vl8;
    #pragma unroll
    for (int j = 0; j < 8; ++j) {
      const size_t ga = (size_t)(c0 + (vseg << 3) + j) * TD3 + 2 * DMODEL + hh * HDIM + vd;
      vh8[j] = (short)qh_g[ga];
      vl8[j] = (short)ql_g[ga];
    }
    *(short8*)&Vth[vd][vseg << 3] = vh8;
    *(short8*)&Vtl[vd][vseg << 3] = vl8;
    __syncthreads();

    // ---- S^T = K . Q^T (3-product split), 4 subtiles of 16 kv cols ----
    f32x4 s4[4];
    #pragma unroll
    for (int sub = 0; sub < 4; ++sub) {
      s4[sub] = (f32x4){0.f, 0.f, 0.f, 0.f};
      const short8 kh = *(const short8*)&Kh[(sub << 4) + fr][fq << 3];
      const short8 kl = *(const short8*)&Kl[(sub << 4) + fr][fq << 3];
      s4[sub] = __builtin_amdgcn_mfma_f32_16x16x32_bf16(kh, fQh, s4[sub], 0, 0, 0);
      s4[sub] = __builtin_amdgcn_mfma_f32_16x16x32_bf16(kh, fQl, s4[sub], 0, 0, 0);
      s4[sub] = __builtin_amdgcn_mfma_f32_16x16x32_bf16(kl, fQh, s4[sub], 0, 0, 0);
    }

    // ---- masked online softmax (lane fr owns q-row fr) ----
    float sv[16];
    float tmax = -3.0e38f;
    #pragma unroll
    for (int sub = 0; sub < 4; ++sub)
      #pragma unroll
      for (int i = 0; i < 4; ++i) {
        const int k = c0 + (sub << 4) + (fq << 2) + i;
        const bool ok = (k < XLEN_C) | (k <= qrow);
        const float val = ok ? s4[sub][i] * SCALE : -3.0e38f;
        sv[(sub << 2) + i] = val;
        tmax = fmaxf(tmax, val);
      }
    tmax = fmaxf(tmax, __shfl_xor(tmax, 16));
    tmax = fmaxf(tmax, __shfl_xor(tmax, 32));
    const float mnew  = fmaxf(m, tmax);
    const float alpha = __expf(m - mnew);
    m = mnew;
    float psum = 0.f;
    unsigned short p_h[16], p_l[16];
    #pragma unroll
    for (int idx = 0; idx < 16; ++idx) {
      const float p = __expf(sv[idx] - mnew);
      psum += p;
      split2(p, p_h[idx], p_l[idx]);
    }
    psum += __shfl_xor(psum, 16);
    psum += __shfl_xor(psum, 32);
    l = l * alpha + psum;

    // write P pair to per-wave LDS: row=q(fr), col=k (72-short pad)
    #pragma unroll
    for (int sub = 0; sub < 4; ++sub) {
      ushort4 uh, ul;
      uh.x = p_h[(sub << 2) + 0]; uh.y = p_h[(sub << 2) + 1];
      uh.z = p_h[(sub << 2) + 2]; uh.w = p_h[(sub << 2) + 3];
      ul.x = p_l[(sub << 2) + 0]; ul.y = p_l[(sub << 2) + 1];
      ul.z = p_l[(sub << 2) + 2]; ul.w = p_l[(sub << 2) + 3];
      *(ushort4*)&Ph[w][fr][(sub << 4) + (fq << 2)] = uh;
      *(ushort4*)&Pl[w][fr][(sub << 4) + (fq << 2)] = ul;
    }

    // rescale O (acc rows are q = fq*4+i -> fetch alpha from lane fq*4+i)
    const float a0 = __shfl(alpha, (fq << 2) + 0);
    const float a1 = __shfl(alpha, (fq << 2) + 1);
    const float a2 = __shfl(alpha, (fq << 2) + 2);
    const float a3 = __shfl(alpha, (fq << 2) + 3);
    #pragma unroll
    for (int df = 0; df < 2; ++df) {
      accO[df][0] *= a0; accO[df][1] *= a1;
      accO[df][2] *= a2; accO[df][3] *= a3;
    }

    // ---- O += P . V (3-product split) ----
    #pragma unroll
    for (int kh2 = 0; kh2 < 2; ++kh2) {
      const short8 pah = *(const short8*)&Ph[w][fr][(kh2 << 5) + (fq << 3)];
      const short8 pal = *(const short8*)&Pl[w][fr][(kh2 << 5) + (fq << 3)];
      #pragma unroll
      for (int df = 0; df < 2; ++df) {
        const short8 vbh = *(const short8*)&Vth[(df << 4) + fr][(kh2 << 5) + (fq << 3)];
        const short8 vbl = *(const short8*)&Vtl[(df << 4) + fr][(kh2 << 5) + (fq << 3)];
        accO[df] = __builtin_amdgcn_mfma_f32_16x16x32_bf16(pah, vbh, accO[df], 0, 0, 0);
        accO[df] = __builtin_amdgcn_mfma_f32_16x16x32_bf16(pal, vbh, accO[df], 0, 0, 0);
        accO[df] = __builtin_amdgcn_mfma_f32_16x16x32_bf16(pah, vbl, accO[df], 0, 0, 0);
      }
    }
  }

  // ---- finalize: divide by l (per q-row), write split bf16 pair ----
  const float linv = 1.f / l;
  const float l0 = __shfl(linv, (fq << 2) + 0);
  const float l1 = __shfl(linv, (fq << 2) + 1);
  const float l2v = __shfl(linv, (fq << 2) + 2);
  const float l3 = __shfl(linv, (fq << 2) + 3);
  #pragma unroll
  for (int df = 0; df < 2; ++df) {
    const int col = hh * HDIM + (df << 4) + fr;
    const float vals[4] = {accO[df][0] * l0, accO[df][1] * l1,
                           accO[df][2] * l2v, accO[df][3] * l3};
    #pragma unroll
    for (int i = 0; i < 4; ++i) {
      const int row = q0 + (w << 4) + (fq << 2) + i;
      unsigned short h, lo; split2(vals[i], h, lo);
      oh_g[(size_t)row * DMODEL + col] = h;
      ol_g[(size_t)row * DMODEL + col] = lo;
    }
  }
}

// ---------------------------------------------------------------------------
// Fused residual add + LayerNorm; emits fp32 AND bf16 hi/lo pair.
// ---------------------------------------------------------------------------
__global__ __launch_bounds__(256) void add_layernorm(const float* __restrict__ h,
                                                     const float* __restrict__ r,
                                                     const float* __restrict__ w,
                                                     const float* __restrict__ b,
                                                     float* __restrict__ out,
                                                     unsigned short* __restrict__ oh,
                                                     unsigned short* __restrict__ ol) {
  const int row = blockIdx.x;
  const int tid = threadIdx.x;
  const float2 hv = *(const float2*)&h[(size_t)row * DMODEL + tid * 2];
  const float2 rv = *(const float2*)&r[(size_t)row * DMODEL + tid * 2];
  const float a0 = hv.x + rv.x, a1 = hv.y + rv.y;
  float s = a0 + a1, ss = a0 * a0 + a1 * a1;
  #pragma unroll
  for (int off = 32; off; off >>= 1) {
    s  += __shfl_xor(s, off);
    ss += __shfl_xor(ss, off);
  }
  __shared__ float sb[4], ssb[4];
  const int wid = tid >> 6;
  if ((tid & 63) == 0) { sb[wid] = s; ssb[wid] = ss; }
  __syncthreads();
  s  = sb[0] + sb[1] + sb[2] + sb[3];
  ss = ssb[0] + ssb[1] + ssb[2] + ssb[3];
  const float mean = s * (1.f / DMODEL);
  const float var  = ss * (1.f / DMODEL) - mean * mean;
  const float rs   = rsqrtf(var + 1e-5f);
  const float2 wv = *(const float2*)&w[tid * 2];
  const float2 bv = *(const float2*)&b[tid * 2];
  const float o0 = (a0 - mean) * rs * wv.x + bv.x;
  const float o1 = (a1 - mean) * rs * wv.y + bv.y;
  float2 o; o.x = o0; o.y = o1;
  *(float2*)&out[(size_t)row * DMODEL + tid * 2] = o;
  unsigned short h0, l0, h1, l1;
  split2(o0, h0, l0); split2(o1, h1, l1);
  ushort2 uh; uh.x = h0; uh.y = h1;
  ushort2 ul; ul.x = l0; ul.y = l1;
  *(ushort2*)&oh[(size_t)row * DMODEL + tid * 2] = uh;
  *(ushort2*)&ol[(size_t)row * DMODEL + tid * 2] = ul;
}

// ---------------------------------------------------------------------------
// Initial: x fp32 -> Hc copy + bf16 hi/lo pair.
// ---------------------------------------------------------------------------
__global__ __launch_bounds__(256) void split_init(const float* __restrict__ x,
                                                  float* __restrict__ f,
                                                  unsigned short* __restrict__ h,
                                                  unsigned short* __restrict__ l,
                                                  int n4) {
  const int i = blockIdx.x * 256 + threadIdx.x;
  if (i >= n4) return;
  const float4 v = *(const float4*)&x[i * 4];
  *(float4*)&f[i * 4] = v;
  const float vf[4] = {v.x, v.y, v.z, v.w};
  ushort4 uh, ul;
  unsigned short hh, ll;
  split2(vf[0], hh, ll); uh.x = hh; ul.x = ll;
  split2(vf[1], hh, ll); uh.y = hh; ul.y = ll;
  split2(vf[2], hh, ll); uh.z = hh; ul.z = ll;
  split2(vf[3], hh, ll); uh.w = hh; ul.w = ll;
  *(ushort4*)&h[i * 4] = uh;
  *(ushort4*)&l[i * 4] = ul;
}

// ---------------------------------------------------------------------------
extern "C" void kernel_launch(void* const* d_in, const int* in_sizes, int n_in,
                              void* d_out, int out_size, void* d_ws, size_t ws_size,
                              hipStream_t stream) {
  const float* x     = (const float*)d_in[0];
  const float* qkv_w = (const float*)d_in[1];
  const float* qkv_b = (const float*)d_in[2];
  const float* out_w = (const float*)d_in[3];
  const float* out_b = (const float*)d_in[4];
  const float* w1    = (const float*)d_in[5];
  const float* b1    = (const float*)d_in[6];
  const float* w2    = (const float*)d_in[7];
  const float* b2    = (const float*)d_in[8];
  const float* nw1   = (const float*)d_in[9];
  const float* nb1   = (const float*)d_in[10];
  const float* nw2   = (const float*)d_in[11];
  const float* nb2   = (const float*)d_in[12];

  // workspace layout (~44 MB)
  char* p = (char*)d_ws;
  float* Hc = (float*)p;              p += (size_t)S_LEN * DMODEL * 4;
  unsigned short* Hh = (unsigned short*)p;   p += (size_t)S_LEN * DMODEL * 2;
  unsigned short* Hl = (unsigned short*)p;   p += (size_t)S_LEN * DMODEL * 2;
  unsigned short* qkvh = (unsigned short*)p; p += (size_t)S_LEN * TD3 * 2;
  unsigned short* qkvl = (unsigned short*)p; p += (size_t)S_LEN * TD3 * 2;
  unsigned short* oath = (unsigned short*)p; p += (size_t)S_LEN * DMODEL * 2;
  unsigned short* oatl = (unsigned short*)p; p += (size_t)S_LEN * DMODEL * 2;
  float* opr = (float*)p;             p += (size_t)S_LEN * DMODEL * 4;
  unsigned short* midh = (unsigned short*)p; p += (size_t)S_LEN * FFDIM * 2;
  unsigned short* midl = (unsigned short*)p; p += (size_t)S_LEN * FFDIM * 2;

  split_init<<<(S_LEN * DMODEL / 4 + 255) / 256, 256, 0, stream>>>(
      x, Hc, Hh, Hl, S_LEN * DMODEL / 4);

  for (int l = 0; l < NLAYER; ++l) {
    const float* qw = qkv_w + (size_t)l * TD3 * DMODEL;
    const float* qb = qkv_b + (size_t)l * TD3;
    const float* ow = out_w + (size_t)l * DMODEL * DMODEL;
    const float* ob = out_b + (size_t)l * DMODEL;
    const float* W1 = w1 + (size_t)l * FFDIM * DMODEL;
    const float* B1 = b1 + (size_t)l * FFDIM;
    const float* W2 = w2 + (size_t)l * DMODEL * FFDIM;
    const float* B2 = b2 + (size_t)l * DMODEL;

    gemm_mfma<4, false, true><<<dim3(TD3 / 64, S_LEN / 128), 256, 0, stream>>>(
        Hh, Hl, qw, qb, nullptr, qkvh, qkvl, TD3, DMODEL);
    attn_mfma<<<dim3(NHEAD, S_LEN / 64), 256, 0, stream>>>(qkvh, qkvl, oath, oatl);
    gemm_mfma<2, false, false><<<dim3(DMODEL / 64, S_LEN / 64), 256, 0, stream>>>(
        oath, oatl, ow, ob, opr, nullptr, nullptr, DMODEL, DMODEL);
    add_layernorm<<<S_LEN, 256, 0, stream>>>(
        Hc, opr, nw1 + (size_t)l * DMODEL, nb1 + (size_t)l * DMODEL, Hc, Hh, Hl);
    gemm_mfma<4, true, true><<<dim3(FFDIM / 64, S_LEN / 128), 256, 0, stream>>>(
        Hh, Hl, W1, B1, nullptr, midh, midl, FFDIM, DMODEL);
    gemm_mfma<2, false, false><<<dim3(DMODEL / 64, S_LEN / 64), 256, 0, stream>>>(
        midh, midl, W2, B2, opr, nullptr, nullptr, DMODEL, FFDIM);
    add_layernorm<<<S_LEN, 256, 0, stream>>>(
        Hc, opr, nw2 + (size_t)l * DMODEL, nb2 + (size_t)l * DMODEL, Hc, Hh, Hl);
  }

  hipMemcpyAsync(d_out, Hc, sizeof(float) * S_LEN * DMODEL,
                 hipMemcpyDeviceToDevice, stream);
}

// Round 6
// 5286.563 us; speedup vs baseline: 2.5296x; 1.1022x over previous
//
#include <hip/hip_runtime.h>
#include <cstddef>

#define S_LEN 2048
#define XLEN_C 1024
#define DMODEL 512
#define NHEAD 16
#define HDIM 32
#define FFDIM 2048
#define NLAYER 24
#define TD3 1536

typedef __attribute__((ext_vector_type(4))) float f32x4;
typedef __attribute__((ext_vector_type(8))) short short8;

// Split fp32 -> bf16 hi + bf16 lo (both RNE). x ~= hi + lo.
__device__ __forceinline__ void split2(float x, unsigned short& h, unsigned short& l) {
  unsigned u = __float_as_uint(x);
  unsigned r = u + 0x7FFFu + ((u >> 16) & 1u);
  h = (unsigned short)(r >> 16);
  float hf = __uint_as_float((unsigned)h << 16);
  float lo = x - hf;                       // exact
  unsigned u2 = __float_as_uint(lo);
  unsigned r2 = u2 + 0x7FFFu + ((u2 >> 16) & 1u);
  l = (unsigned short)(r2 >> 16);
}

// ---------------------------------------------------------------------------
// MFMA GEMM. A pre-split bf16 pair; B either pre-split (PRESPLIT_B) or fp32
// split in-kernel. C = A @ B^T + bias. BM=32*WMF, BN=64, BK=32.
// 4 waves (2x2); 3-product split MFMA (AhBh + AhBl + AlBh) = fp32-grade.
// LDS rows padded to 40 shorts: b128 accesses bank-balanced.
// ---------------------------------------------------------------------------
template<int WMF, bool RELU, bool SPLIT_OUT, bool PRESPLIT_B>
__global__ __launch_bounds__(256) void gemm_mfma(const unsigned short* __restrict__ Ahg,
                                                 const unsigned short* __restrict__ Alg,
                                                 const float* __restrict__ Bg,
                                                 const unsigned short* __restrict__ Bhg,
                                                 const unsigned short* __restrict__ Blg,
                                                 const float* __restrict__ bias,
                                                 float* __restrict__ Cf,
                                                 unsigned short* __restrict__ Ch,
                                                 unsigned short* __restrict__ Cl,
                                                 int N, int K) {
  constexpr int BM = 32 * WMF;
  __shared__ __align__(16) unsigned short Ahs[BM][40];
  __shared__ __align__(16) unsigned short Als[BM][40];
  __shared__ __align__(16) unsigned short Bhs[64][40];
  __shared__ __align__(16) unsigned short Bls[64][40];

  const int tid  = threadIdx.x;
  const int m0   = blockIdx.y * BM;
  const int n0   = blockIdx.x << 6;
  const int w    = tid >> 6;
  const int lane = tid & 63;
  const int wm   = (w >> 1) * (16 * WMF);
  const int wn   = (w & 1) << 5;
  const int fr   = lane & 15;
  const int fq   = lane >> 4;

  const int br = tid >> 2, bc = (tid & 3) << 3;

  f32x4 acc[WMF][2];
  #pragma unroll
  for (int i = 0; i < WMF; ++i)
    #pragma unroll
    for (int j = 0; j < 2; ++j)
      acc[i][j] = (f32x4){0.f, 0.f, 0.f, 0.f};

  for (int k0 = 0; k0 < K; k0 += 32) {
    short8 bh, bl;
    if (PRESPLIT_B) {
      bh = *(const short8*)&Bhg[(size_t)(n0 + br) * K + k0 + bc];
      bl = *(const short8*)&Blg[(size_t)(n0 + br) * K + k0 + bc];
    } else {
      float4 b0 = *(const float4*)&Bg[(size_t)(n0 + br) * K + k0 + bc];
      float4 b1 = *(const float4*)&Bg[(size_t)(n0 + br) * K + k0 + bc + 4];
      const float bf[8] = {b0.x, b0.y, b0.z, b0.w, b1.x, b1.y, b1.z, b1.w};
      #pragma unroll
      for (int i = 0; i < 8; ++i) {
        unsigned short h, lo; split2(bf[i], h, lo);
        bh[i] = (short)h; bl[i] = (short)lo;
      }
    }
    short8 a_h[(BM * 4) / 256], a_l[(BM * 4) / 256];
    #pragma unroll
    for (int it = 0; it < (BM * 4) / 256; ++it) {
      const int c = tid + (it << 8);
      const int arow = c >> 2, acol = (c & 3) << 3;
      a_h[it] = *(const short8*)&Ahg[(size_t)(m0 + arow) * K + k0 + acol];
      a_l[it] = *(const short8*)&Alg[(size_t)(m0 + arow) * K + k0 + acol];
    }
    __syncthreads();
    #pragma unroll
    for (int it = 0; it < (BM * 4) / 256; ++it) {
      const int c = tid + (it << 8);
      const int arow = c >> 2, acol = (c & 3) << 3;
      *(short8*)&Ahs[arow][acol] = a_h[it];
      *(short8*)&Als[arow][acol] = a_l[it];
    }
    *(short8*)&Bhs[br][bc] = bh;
    *(short8*)&Bls[br][bc] = bl;
    __syncthreads();

    short8 fah[WMF], fal[WMF], fbh[2], fbl[2];
    #pragma unroll
    for (int fm = 0; fm < WMF; ++fm) {
      fah[fm] = *(const short8*)&Ahs[wm + (fm << 4) + fr][fq << 3];
      fal[fm] = *(const short8*)&Als[wm + (fm << 4) + fr][fq << 3];
    }
    #pragma unroll
    for (int fn = 0; fn < 2; ++fn) {
      fbh[fn] = *(const short8*)&Bhs[wn + (fn << 4) + fr][fq << 3];
      fbl[fn] = *(const short8*)&Bls[wn + (fn << 4) + fr][fq << 3];
    }
    #pragma unroll
    for (int fm = 0; fm < WMF; ++fm)
      #pragma unroll
      for (int fn = 0; fn < 2; ++fn) {
        acc[fm][fn] = __builtin_amdgcn_mfma_f32_16x16x32_bf16(fah[fm], fbh[fn], acc[fm][fn], 0, 0, 0);
        acc[fm][fn] = __builtin_amdgcn_mfma_f32_16x16x32_bf16(fah[fm], fbl[fn], acc[fm][fn], 0, 0, 0);
        acc[fm][fn] = __builtin_amdgcn_mfma_f32_16x16x32_bf16(fal[fm], fbh[fn], acc[fm][fn], 0, 0, 0);
      }
  }

  #pragma unroll
  for (int fn = 0; fn < 2; ++fn) {
    const int col = n0 + wn + (fn << 4) + fr;
    const float bb = bias[col];
    #pragma unroll
    for (int fm = 0; fm < WMF; ++fm) {
      const int rbase = m0 + wm + (fm << 4) + (fq << 2);
      #pragma unroll
      for (int i = 0; i < 4; ++i) {
        float v = acc[fm][fn][i] + bb;
        if (RELU) v = fmaxf(v, 0.f);
        const size_t idx = (size_t)(rbase + i) * N + col;
        if (SPLIT_OUT) {
          unsigned short h, lo; split2(v, h, lo);
          Ch[idx] = h; Cl[idx] = lo;
        } else {
          Cf[idx] = v;
        }
      }
    }
  }
}

// ---------------------------------------------------------------------------
// V transpose: qkv V-part [seq][h*32+d] -> Vt[h][d][seq] (hi & lo pair).
// Block = (head, 64-seq tile). Coalesced loads, LDS transpose, coalesced
// stores.
// ---------------------------------------------------------------------------
__global__ __launch_bounds__(256) void transpose_v(const unsigned short* __restrict__ qh,
                                                   const unsigned short* __restrict__ ql,
                                                   unsigned short* __restrict__ vth,
                                                   unsigned short* __restrict__ vtl) {
  const int hh  = blockIdx.x;
  const int t0  = blockIdx.y << 6;
  const int tid = threadIdx.x;
  __shared__ unsigned short Th[64][40];
  __shared__ unsigned short Tl[64][40];
  const int lseq = tid >> 2, dg = (tid & 3) << 3;
  const size_t src = (size_t)(t0 + lseq) * TD3 + 2 * DMODEL + (hh << 5) + dg;
  *(short8*)&Th[lseq][dg] = *(const short8*)&qh[src];
  *(short8*)&Tl[lseq][dg] = *(const short8*)&ql[src];
  __syncthreads();
  const int d = tid >> 3, sg = (tid & 7) << 3;
  short8 oh, ol;
  #pragma unroll
  for (int j = 0; j < 8; ++j) { oh[j] = (short)Th[sg + j][d]; ol[j] = (short)Tl[sg + j][d]; }
  const size_t dst = ((size_t)(hh << 5) + d) * S_LEN + t0 + sg;
  *(short8*)&vth[dst] = oh;
  *(short8*)&vtl[dst] = ol;
}

// ---------------------------------------------------------------------------
// MFMA flash attention, fp32-grade. Block = (head, 64 q-rows), 4 waves.
// Swapped QK^T (S^T = K.Q^T). V read pre-transposed from Vt (coalesced
// short8 staging). Softmax in exp2 domain.
// ---------------------------------------------------------------------------
__global__ __launch_bounds__(256) void attn_mfma(const unsigned short* __restrict__ qh_g,
                                                 const unsigned short* __restrict__ ql_g,
                                                 const unsigned short* __restrict__ vth_g,
                                                 const unsigned short* __restrict__ vtl_g,
                                                 unsigned short* __restrict__ oh_g,
                                                 unsigned short* __restrict__ ol_g) {
  const int hh  = blockIdx.x;
  const int q0  = blockIdx.y << 6;
  const int tid = threadIdx.x;
  const int w   = tid >> 6;
  const int lane = tid & 63;
  const int fr = lane & 15;
  const int fq = lane >> 4;
  // 1/sqrt(32) * log2(e): softmax computed in exp2 domain
  constexpr float SCL2 = 0.17677669529663687f * 1.44269504088896341f;

  __shared__ __align__(16) unsigned short Kh[64][40];
  __shared__ __align__(16) unsigned short Kl[64][40];
  __shared__ __align__(16) unsigned short Vth[32][72];
  __shared__ __align__(16) unsigned short Vtl[32][72];
  __shared__ __align__(16) unsigned short Ph[4][16][72];
  __shared__ __align__(16) unsigned short Pl[4][16][72];

  const int qrow = q0 + (w << 4) + fr;
  const short8 fQh = *(const short8*)&qh_g[(size_t)qrow * TD3 + hh * HDIM + (fq << 3)];
  const short8 fQl = *(const short8*)&ql_g[(size_t)qrow * TD3 + hh * HDIM + (fq << 3)];

  float m = -3.0e38f, l = 0.f;
  f32x4 accO[2];
  accO[0] = (f32x4){0.f, 0.f, 0.f, 0.f};
  accO[1] = (f32x4){0.f, 0.f, 0.f, 0.f};

  const int kend   = (q0 < XLEN_C) ? XLEN_C : (q0 + 64);
  const int ntiles = kend >> 6;

  const int krow = tid >> 2, kcol = (tid & 3) << 3;  // K staging
  const int vd = tid >> 3, vseg = tid & 7;           // V staging from Vt

  for (int t = 0; t < ntiles; ++t) {
    const int c0 = t << 6;
    __syncthreads();
    *(short8*)&Kh[krow][kcol] =
        *(const short8*)&qh_g[(size_t)(c0 + krow) * TD3 + DMODEL + hh * HDIM + kcol];
    *(short8*)&Kl[krow][kcol] =
        *(const short8*)&ql_g[(size_t)(c0 + krow) * TD3 + DMODEL + hh * HDIM + kcol];
    const size_t vsrc = ((size_t)(hh << 5) + vd) * S_LEN + c0 + (vseg << 3);
    *(short8*)&Vth[vd][vseg << 3] = *(const short8*)&vth_g[vsrc];
    *(short8*)&Vtl[vd][vseg << 3] = *(const short8*)&vtl_g[vsrc];
    __syncthreads();

    // ---- S^T = K . Q^T (3-product split), 4 subtiles of 16 kv cols ----
    f32x4 s4[4];
    #pragma unroll
    for (int sub = 0; sub < 4; ++sub) {
      s4[sub] = (f32x4){0.f, 0.f, 0.f, 0.f};
      const short8 kh = *(const short8*)&Kh[(sub << 4) + fr][fq << 3];
      const short8 kl = *(const short8*)&Kl[(sub << 4) + fr][fq << 3];
      s4[sub] = __builtin_amdgcn_mfma_f32_16x16x32_bf16(kh, fQh, s4[sub], 0, 0, 0);
      s4[sub] = __builtin_amdgcn_mfma_f32_16x16x32_bf16(kh, fQl, s4[sub], 0, 0, 0);
      s4[sub] = __builtin_amdgcn_mfma_f32_16x16x32_bf16(kl, fQh, s4[sub], 0, 0, 0);
    }

    // ---- masked online softmax (exp2 domain; lane fr owns q-row fr) ----
    float sv[16];
    float tmax = -3.0e38f;
    #pragma unroll
    for (int sub = 0; sub < 4; ++sub)
      #pragma unroll
      for (int i = 0; i < 4; ++i) {
        const int k = c0 + (sub << 4) + (fq << 2) + i;
        const bool ok = (k < XLEN_C) | (k <= qrow);
        const float val = ok ? s4[sub][i] * SCL2 : -3.0e38f;
        sv[(sub << 2) + i] = val;
        tmax = fmaxf(tmax, val);
      }
    tmax = fmaxf(tmax, __shfl_xor(tmax, 16));
    tmax = fmaxf(tmax, __shfl_xor(tmax, 32));
    const float mnew  = fmaxf(m, tmax);
    const float alpha = exp2f(m - mnew);
    m = mnew;
    float psum = 0.f;
    unsigned short p_h[16], p_l[16];
    #pragma unroll
    for (int idx = 0; idx < 16; ++idx) {
      const float p = exp2f(sv[idx] - mnew);
      psum += p;
      split2(p, p_h[idx], p_l[idx]);
    }
    psum += __shfl_xor(psum, 16);
    psum += __shfl_xor(psum, 32);
    l = l * alpha + psum;

    #pragma unroll
    for (int sub = 0; sub < 4; ++sub) {
      ushort4 uh, ul;
      uh.x = p_h[(sub << 2) + 0]; uh.y = p_h[(sub << 2) + 1];
      uh.z = p_h[(sub << 2) + 2]; uh.w = p_h[(sub << 2) + 3];
      ul.x = p_l[(sub << 2) + 0]; ul.y = p_l[(sub << 2) + 1];
      ul.z = p_l[(sub << 2) + 2]; ul.w = p_l[(sub << 2) + 3];
      *(ushort4*)&Ph[w][fr][(sub << 4) + (fq << 2)] = uh;
      *(ushort4*)&Pl[w][fr][(sub << 4) + (fq << 2)] = ul;
    }

    const float a0 = __shfl(alpha, (fq << 2) + 0);
    const float a1 = __shfl(alpha, (fq << 2) + 1);
    const float a2 = __shfl(alpha, (fq << 2) + 2);
    const float a3 = __shfl(alpha, (fq << 2) + 3);
    #pragma unroll
    for (int df = 0; df < 2; ++df) {
      accO[df][0] *= a0; accO[df][1] *= a1;
      accO[df][2] *= a2; accO[df][3] *= a3;
    }

    // ---- O += P . V (3-product split) ----
    #pragma unroll
    for (int kh2 = 0; kh2 < 2; ++kh2) {
      const short8 pah = *(const short8*)&Ph[w][fr][(kh2 << 5) + (fq << 3)];
      const short8 pal = *(const short8*)&Pl[w][fr][(kh2 << 5) + (fq << 3)];
      #pragma unroll
      for (int df = 0; df < 2; ++df) {
        const short8 vbh = *(const short8*)&Vth[(df << 4) + fr][(kh2 << 5) + (fq << 3)];
        const short8 vbl = *(const short8*)&Vtl[(df << 4) + fr][(kh2 << 5) + (fq << 3)];
        accO[df] = __builtin_amdgcn_mfma_f32_16x16x32_bf16(pah, vbh, accO[df], 0, 0, 0);
        accO[df] = __builtin_amdgcn_mfma_f32_16x16x32_bf16(pal, vbh, accO[df], 0, 0, 0);
        accO[df] = __builtin_amdgcn_mfma_f32_16x16x32_bf16(pah, vbl, accO[df], 0, 0, 0);
      }
    }
  }

  const float linv = 1.f / l;
  const float l0 = __shfl(linv, (fq << 2) + 0);
  const float l1 = __shfl(linv, (fq << 2) + 1);
  const float l2v = __shfl(linv, (fq << 2) + 2);
  const float l3 = __shfl(linv, (fq << 2) + 3);
  #pragma unroll
  for (int df = 0; df < 2; ++df) {
    const int col = hh * HDIM + (df << 4) + fr;
    const float vals[4] = {accO[df][0] * l0, accO[df][1] * l1,
                           accO[df][2] * l2v, accO[df][3] * l3};
    #pragma unroll
    for (int i = 0; i < 4; ++i) {
      const int row = q0 + (w << 4) + (fq << 2) + i;
      unsigned short h, lo; split2(vals[i], h, lo);
      oh_g[(size_t)row * DMODEL + col] = h;
      ol_g[(size_t)row * DMODEL + col] = lo;
    }
  }
}

// ---------------------------------------------------------------------------
// Fused residual add + LayerNorm; emits fp32 AND bf16 hi/lo pair.
// ---------------------------------------------------------------------------
__global__ __launch_bounds__(256) void add_layernorm(const float* __restrict__ h,
                                                     const float* __restrict__ r,
                                                     const float* __restrict__ w,
                                                     const float* __restrict__ b,
                                                     float* __restrict__ out,
                                                     unsigned short* __restrict__ oh,
                                                     unsigned short* __restrict__ ol) {
  const int row = blockIdx.x;
  const int tid = threadIdx.x;
  const float2 hv = *(const float2*)&h[(size_t)row * DMODEL + tid * 2];
  const float2 rv = *(const float2*)&r[(size_t)row * DMODEL + tid * 2];
  const float a0 = hv.x + rv.x, a1 = hv.y + rv.y;
  float s = a0 + a1, ss = a0 * a0 + a1 * a1;
  #pragma unroll
  for (int off = 32; off; off >>= 1) {
    s  += __shfl_xor(s, off);
    ss += __shfl_xor(ss, off);
  }
  __shared__ float sb[4], ssb[4];
  const int wid = tid >> 6;
  if ((tid & 63) == 0) { sb[wid] = s; ssb[wid] = ss; }
  __syncthreads();
  s  = sb[0] + sb[1] + sb[2] + sb[3];
  ss = ssb[0] + ssb[1] + ssb[2] + ssb[3];
  const float mean = s * (1.f / DMODEL);
  const float var  = ss * (1.f / DMODEL) - mean * mean;
  const float rs   = rsqrtf(var + 1e-5f);
  const float2 wv = *(const float2*)&w[tid * 2];
  const float2 bv = *(const float2*)&b[tid * 2];
  const float o0 = (a0 - mean) * rs * wv.x + bv.x;
  const float o1 = (a1 - mean) * rs * wv.y + bv.y;
  float2 o; o.x = o0; o.y = o1;
  *(float2*)&out[(size_t)row * DMODEL + tid * 2] = o;
  unsigned short h0, l0, h1, l1;
  split2(o0, h0, l0); split2(o1, h1, l1);
  ushort2 uh; uh.x = h0; uh.y = h1;
  ushort2 ul; ul.x = l0; ul.y = l1;
  *(ushort2*)&oh[(size_t)row * DMODEL + tid * 2] = uh;
  *(ushort2*)&ol[(size_t)row * DMODEL + tid * 2] = ul;
}

// ---------------------------------------------------------------------------
// split fp32 -> bf16 pair; with optional fp32 passthrough (for x init).
// n4 = count/4, exact multiple of 256 blocks assumed by launch config.
// ---------------------------------------------------------------------------
__global__ __launch_bounds__(256) void split_w(const float* __restrict__ src,
                                               unsigned short* __restrict__ h,
                                               unsigned short* __restrict__ l) {
  const int i = blockIdx.x * 256 + threadIdx.x;
  const float4 v = *(const float4*)&src[(size_t)i * 4];
  const float vf[4] = {v.x, v.y, v.z, v.w};
  ushort4 uh, ul;
  unsigned short hh, ll;
  split2(vf[0], hh, ll); uh.x = hh; ul.x = ll;
  split2(vf[1], hh, ll); uh.y = hh; ul.y = ll;
  split2(vf[2], hh, ll); uh.z = hh; ul.z = ll;
  split2(vf[3], hh, ll); uh.w = hh; ul.w = ll;
  *(ushort4*)&h[(size_t)i * 4] = uh;
  *(ushort4*)&l[(size_t)i * 4] = ul;
}

__global__ __launch_bounds__(256) void split_init(const float* __restrict__ x,
                                                  float* __restrict__ f,
                                                  unsigned short* __restrict__ h,
                                                  unsigned short* __restrict__ l,
                                                  int n4) {
  const int i = blockIdx.x * 256 + threadIdx.x;
  if (i >= n4) return;
  const float4 v = *(const float4*)&x[(size_t)i * 4];
  *(float4*)&f[(size_t)i * 4] = v;
  const float vf[4] = {v.x, v.y, v.z, v.w};
  ushort4 uh, ul;
  unsigned short hh, ll;
  split2(vf[0], hh, ll); uh.x = hh; ul.x = ll;
  split2(vf[1], hh, ll); uh.y = hh; ul.y = ll;
  split2(vf[2], hh, ll); uh.z = hh; ul.z = ll;
  split2(vf[3], hh, ll); uh.w = hh; ul.w = ll;
  *(ushort4*)&h[(size_t)i * 4] = uh;
  *(ushort4*)&l[(size_t)i * 4] = ul;
}

// ---------------------------------------------------------------------------
extern "C" void kernel_launch(void* const* d_in, const int* in_sizes, int n_in,
                              void* d_out, int out_size, void* d_ws, size_t ws_size,
                              hipStream_t stream) {
  const float* x     = (const float*)d_in[0];
  const float* qkv_w = (const float*)d_in[1];
  const float* qkv_b = (const float*)d_in[2];
  const float* out_w = (const float*)d_in[3];
  const float* out_b = (const float*)d_in[4];
  const float* w1    = (const float*)d_in[5];
  const float* b1    = (const float*)d_in[6];
  const float* w2    = (const float*)d_in[7];
  const float* b2    = (const float*)d_in[8];
  const float* nw1   = (const float*)d_in[9];
  const float* nb1   = (const float*)d_in[10];
  const float* nw2   = (const float*)d_in[11];
  const float* nb2   = (const float*)d_in[12];

  // ---- workspace layout ----
  char* p = (char*)d_ws;
  float* Hc = (float*)p;                     p += (size_t)S_LEN * DMODEL * 4;
  unsigned short* Hh = (unsigned short*)p;   p += (size_t)S_LEN * DMODEL * 2;
  unsigned short* Hl = (unsigned short*)p;   p += (size_t)S_LEN * DMODEL * 2;
  unsigned short* qkvh = (unsigned short*)p; p += (size_t)S_LEN * TD3 * 2;
  unsigned short* qkvl = (unsigned short*)p; p += (size_t)S_LEN * TD3 * 2;
  unsigned short* oath = (unsigned short*)p; p += (size_t)S_LEN * DMODEL * 2;
  unsigned short* oatl = (unsigned short*)p; p += (size_t)S_LEN * DMODEL * 2;
  float* opr = (float*)p;                    p += (size_t)S_LEN * DMODEL * 4;
  unsigned short* midh = (unsigned short*)p; p += (size_t)S_LEN * FFDIM * 2;
  unsigned short* midl = (unsigned short*)p; p += (size_t)S_LEN * FFDIM * 2;
  unsigned short* vth = (unsigned short*)p;  p += (size_t)S_LEN * DMODEL * 2;
  unsigned short* vtl = (unsigned short*)p;  p += (size_t)S_LEN * DMODEL * 2;
  // pre-split weights (288 MB) — only if ws is big enough
  unsigned short* qkvWh = (unsigned short*)p; p += (size_t)NLAYER * TD3 * DMODEL * 2;
  unsigned short* qkvWl = (unsigned short*)p; p += (size_t)NLAYER * TD3 * DMODEL * 2;
  unsigned short* outWh = (unsigned short*)p; p += (size_t)NLAYER * DMODEL * DMODEL * 2;
  unsigned short* outWl = (unsigned short*)p; p += (size_t)NLAYER * DMODEL * DMODEL * 2;
  unsigned short* w1h = (unsigned short*)p;   p += (size_t)NLAYER * FFDIM * DMODEL * 2;
  unsigned short* w1l = (unsigned short*)p;   p += (size_t)NLAYER * FFDIM * DMODEL * 2;
  unsigned short* w2h = (unsigned short*)p;   p += (size_t)NLAYER * DMODEL * FFDIM * 2;
  unsigned short* w2l = (unsigned short*)p;   p += (size_t)NLAYER * DMODEL * FFDIM * 2;
  const size_t need = (size_t)(p - (char*)d_ws);
  const bool presplit = ws_size >= need;

  split_init<<<(S_LEN * DMODEL / 4 + 255) / 256, 256, 0, stream>>>(
      x, Hc, Hh, Hl, S_LEN * DMODEL / 4);

  if (presplit) {
    split_w<<<NLAYER * TD3 * DMODEL / 1024, 256, 0, stream>>>(qkv_w, qkvWh, qkvWl);
    split_w<<<NLAYER * DMODEL * DMODEL / 1024, 256, 0, stream>>>(out_w, outWh, outWl);
    split_w<<<NLAYER * FFDIM * DMODEL / 1024, 256, 0, stream>>>(w1, w1h, w1l);
    split_w<<<NLAYER * DMODEL * FFDIM / 1024, 256, 0, stream>>>(w2, w2h, w2l);
  }

  for (int l = 0; l < NLAYER; ++l) {
    const float* qw = qkv_w + (size_t)l * TD3 * DMODEL;
    const float* qb = qkv_b + (size_t)l * TD3;
    const float* ow = out_w + (size_t)l * DMODEL * DMODEL;
    const float* ob = out_b + (size_t)l * DMODEL;
    const float* W1 = w1 + (size_t)l * FFDIM * DMODEL;
    const float* B1 = b1 + (size_t)l * FFDIM;
    const float* W2 = w2 + (size_t)l * DMODEL * FFDIM;
    const float* B2 = b2 + (size_t)l * DMODEL;

    if (presplit) {
      const unsigned short* qwh = qkvWh + (size_t)l * TD3 * DMODEL;
      const unsigned short* qwl = qkvWl + (size_t)l * TD3 * DMODEL;
      const unsigned short* owh = outWh + (size_t)l * DMODEL * DMODEL;
      const unsigned short* owl = outWl + (size_t)l * DMODEL * DMODEL;
      const unsigned short* W1h = w1h + (size_t)l * FFDIM * DMODEL;
      const unsigned short* W1l = w1l + (size_t)l * FFDIM * DMODEL;
      const unsigned short* W2h = w2h + (size_t)l * DMODEL * FFDIM;
      const unsigned short* W2l = w2l + (size_t)l * DMODEL * FFDIM;

      gemm_mfma<4, false, true, true><<<dim3(TD3 / 64, S_LEN / 128), 256, 0, stream>>>(
          Hh, Hl, nullptr, qwh, qwl, qb, nullptr, qkvh, qkvl, TD3, DMODEL);
      transpose_v<<<dim3(NHEAD, S_LEN / 64), 256, 0, stream>>>(qkvh, qkvl, vth, vtl);
      attn_mfma<<<dim3(NHEAD, S_LEN / 64), 256, 0, stream>>>(qkvh, qkvl, vth, vtl, oath, oatl);
      gemm_mfma<2, false, false, true><<<dim3(DMODEL / 64, S_LEN / 64), 256, 0, stream>>>(
          oath, oatl, nullptr, owh, owl, ob, opr, nullptr, nullptr, DMODEL, DMODEL);
      add_layernorm<<<S_LEN, 256, 0, stream>>>(
          Hc, opr, nw1 + (size_t)l * DMODEL, nb1 + (size_t)l * DMODEL, Hc, Hh, Hl);
      gemm_mfma<4, true, true, true><<<dim3(FFDIM / 64, S_LEN / 128), 256, 0, stream>>>(
          Hh, Hl, nullptr, W1h, W1l, B1, nullptr, midh, midl, FFDIM, DMODEL);
      gemm_mfma<2, false, false, true><<<dim3(DMODEL / 64, S_LEN / 64), 256, 0, stream>>>(
          midh, midl, nullptr, W2h, W2l, B2, opr, nullptr, nullptr, DMODEL, FFDIM);
      add_layernorm<<<S_LEN, 256, 0, stream>>>(
          Hc, opr, nw2 + (size_t)l * DMODEL, nb2 + (size_t)l * DMODEL, Hc, Hh, Hl);
    } else {
      gemm_mfma<4, false, true, false><<<dim3(TD3 / 64, S_LEN / 128), 256, 0, stream>>>(
          Hh, Hl, qw, nullptr, nullptr, qb, nullptr, qkvh, qkvl, TD3, DMODEL);
      transpose_v<<<dim3(NHEAD, S_LEN / 64), 256, 0, stream>>>(qkvh, qkvl, vth, vtl);
      attn_mfma<<<dim3(NHEAD, S_LEN / 64), 256, 0, stream>>>(qkvh, qkvl, vth, vtl, oath, oatl);
      gemm_mfma<2, false, false, false><<<dim3(DMODEL / 64, S_LEN / 64), 256, 0, stream>>>(
          oath, oatl, ow, nullptr, nullptr, ob, opr, nullptr, nullptr, DMODEL, DMODEL);
      add_layernorm<<<S_LEN, 256, 0, stream>>>(
          Hc, opr, nw1 + (size_t)l * DMODEL, nb1 + (size_t)l * DMODEL, Hc, Hh, Hl);
      gemm_mfma<4, true, true, false><<<dim3(FFDIM / 64, S_LEN / 128), 256, 0, stream>>>(
          Hh, Hl, W1, nullptr, nullptr, B1, nullptr, midh, midl, FFDIM, DMODEL);
      gemm_mfma<2, false, false, false><<<dim3(DMODEL / 64, S_LEN / 64), 256, 0, stream>>>(
          midh, midl, W2, nullptr, nullptr, B2, opr, nullptr, nullptr, DMODEL, FFDIM);
      add_layernorm<<<S_LEN, 256, 0, stream>>>(
          Hc, opr, nw2 + (size_t)l * DMODEL, nb2 + (size_t)l * DMODEL, Hc, Hh, Hl);
    }
  }

  hipMemcpyAsync(d_out, Hc, sizeof(float) * S_LEN * DMODEL,
                 hipMemcpyDeviceToDevice, stream);
}

// Round 8
// 4675.292 us; speedup vs baseline: 2.8603x; 1.1307x over previous
//
#include <hip/hip_runtime.h>
#include <cstddef>

#define S_LEN 2048
#define XLEN_C 1024
#define DMODEL 512
#define NHEAD 16
#define HDIM 32
#define FFDIM 2048
#define NLAYER 24
#define TD3 1536
#define NQT 32          // S_LEN / 64 query tiles

typedef __attribute__((ext_vector_type(4))) float f32x4;
typedef __attribute__((ext_vector_type(8))) short short8;

// Split fp32 -> bf16 hi + bf16 lo (both RNE). x ~= hi + lo.
__device__ __forceinline__ void split2(float x, unsigned short& h, unsigned short& l) {
  unsigned u = __float_as_uint(x);
  unsigned r = u + 0x7FFFu + ((u >> 16) & 1u);
  h = (unsigned short)(r >> 16);
  float hf = __uint_as_float((unsigned)h << 16);
  float lo = x - hf;                       // exact
  unsigned u2 = __float_as_uint(lo);
  unsigned r2 = u2 + 0x7FFFu + ((u2 >> 16) & 1u);
  l = (unsigned short)(r2 >> 16);
}

// ---------------------------------------------------------------------------
// MFMA GEMM. A pre-split bf16 pair; B pre-split (PRESPLIT_B) or fp32 split
// in-kernel. C = A @ B^T + bias. BM=32*WMF, BN=64, BK=32. 4 waves (2x2).
// 3-product split MFMA (AhBh + AhBl + AlBh) = fp32-grade.
// ---------------------------------------------------------------------------
template<int WMF, bool RELU, bool SPLIT_OUT, bool PRESPLIT_B>
__global__ __launch_bounds__(256) void gemm_mfma(const unsigned short* __restrict__ Ahg,
                                                 const unsigned short* __restrict__ Alg,
                                                 const float* __restrict__ Bg,
                                                 const unsigned short* __restrict__ Bhg,
                                                 const unsigned short* __restrict__ Blg,
                                                 const float* __restrict__ bias,
                                                 float* __restrict__ Cf,
                                                 unsigned short* __restrict__ Ch,
                                                 unsigned short* __restrict__ Cl,
                                                 int N, int K) {
  constexpr int BM = 32 * WMF;
  __shared__ __align__(16) unsigned short Ahs[BM][40];
  __shared__ __align__(16) unsigned short Als[BM][40];
  __shared__ __align__(16) unsigned short Bhs[64][40];
  __shared__ __align__(16) unsigned short Bls[64][40];

  const int tid  = threadIdx.x;
  const int m0   = blockIdx.y * BM;
  const int n0   = blockIdx.x << 6;
  const int w    = tid >> 6;
  const int lane = tid & 63;
  const int wm   = (w >> 1) * (16 * WMF);
  const int wn   = (w & 1) << 5;
  const int fr   = lane & 15;
  const int fq   = lane >> 4;

  const int br = tid >> 2, bc = (tid & 3) << 3;

  f32x4 acc[WMF][2];
  #pragma unroll
  for (int i = 0; i < WMF; ++i)
    #pragma unroll
    for (int j = 0; j < 2; ++j)
      acc[i][j] = (f32x4){0.f, 0.f, 0.f, 0.f};

  for (int k0 = 0; k0 < K; k0 += 32) {
    short8 bh, bl;
    if (PRESPLIT_B) {
      bh = *(const short8*)&Bhg[(size_t)(n0 + br) * K + k0 + bc];
      bl = *(const short8*)&Blg[(size_t)(n0 + br) * K + k0 + bc];
    } else {
      float4 b0 = *(const float4*)&Bg[(size_t)(n0 + br) * K + k0 + bc];
      float4 b1 = *(const float4*)&Bg[(size_t)(n0 + br) * K + k0 + bc + 4];
      const float bf[8] = {b0.x, b0.y, b0.z, b0.w, b1.x, b1.y, b1.z, b1.w};
      #pragma unroll
      for (int i = 0; i < 8; ++i) {
        unsigned short h, lo; split2(bf[i], h, lo);
        bh[i] = (short)h; bl[i] = (short)lo;
      }
    }
    short8 a_h[(BM * 4) / 256], a_l[(BM * 4) / 256];
    #pragma unroll
    for (int it = 0; it < (BM * 4) / 256; ++it) {
      const int c = tid + (it << 8);
      const int arow = c >> 2, acol = (c & 3) << 3;
      a_h[it] = *(const short8*)&Ahg[(size_t)(m0 + arow) * K + k0 + acol];
      a_l[it] = *(const short8*)&Alg[(size_t)(m0 + arow) * K + k0 + acol];
    }
    __syncthreads();
    #pragma unroll
    for (int it = 0; it < (BM * 4) / 256; ++it) {
      const int c = tid + (it << 8);
      const int arow = c >> 2, acol = (c & 3) << 3;
      *(short8*)&Ahs[arow][acol] = a_h[it];
      *(short8*)&Als[arow][acol] = a_l[it];
    }
    *(short8*)&Bhs[br][bc] = bh;
    *(short8*)&Bls[br][bc] = bl;
    __syncthreads();

    short8 fah[WMF], fal[WMF], fbh[2], fbl[2];
    #pragma unroll
    for (int fm = 0; fm < WMF; ++fm) {
      fah[fm] = *(const short8*)&Ahs[wm + (fm << 4) + fr][fq << 3];
      fal[fm] = *(const short8*)&Als[wm + (fm << 4) + fr][fq << 3];
    }
    #pragma unroll
    for (int fn = 0; fn < 2; ++fn) {
      fbh[fn] = *(const short8*)&Bhs[wn + (fn << 4) + fr][fq << 3];
      fbl[fn] = *(const short8*)&Bls[wn + (fn << 4) + fr][fq << 3];
    }
    #pragma unroll
    for (int fm = 0; fm < WMF; ++fm)
      #pragma unroll
      for (int fn = 0; fn < 2; ++fn) {
        acc[fm][fn] = __builtin_amdgcn_mfma_f32_16x16x32_bf16(fah[fm], fbh[fn], acc[fm][fn], 0, 0, 0);
        acc[fm][fn] = __builtin_amdgcn_mfma_f32_16x16x32_bf16(fah[fm], fbl[fn], acc[fm][fn], 0, 0, 0);
        acc[fm][fn] = __builtin_amdgcn_mfma_f32_16x16x32_bf16(fal[fm], fbh[fn], acc[fm][fn], 0, 0, 0);
      }
  }

  #pragma unroll
  for (int fn = 0; fn < 2; ++fn) {
    const int col = n0 + wn + (fn << 4) + fr;
    const float bb = bias[col];
    #pragma unroll
    for (int fm = 0; fm < WMF; ++fm) {
      const int rbase = m0 + wm + (fm << 4) + (fq << 2);
      #pragma unroll
      for (int i = 0; i < 4; ++i) {
        float v = acc[fm][fn][i] + bb;
        if (RELU) v = fmaxf(v, 0.f);
        const size_t idx = (size_t)(rbase + i) * N + col;
        if (SPLIT_OUT) {
          unsigned short h, lo; split2(v, h, lo);
          Ch[idx] = h; Cl[idx] = lo;
        } else {
          Cf[idx] = v;
        }
      }
    }
  }
}

// ---------------------------------------------------------------------------
// V transpose: qkv V-part [seq][h*32+d] -> Vt[h][d][seq] (hi & lo pair).
// ---------------------------------------------------------------------------
__global__ __launch_bounds__(256) void transpose_v(const unsigned short* __restrict__ qh,
                                                   const unsigned short* __restrict__ ql,
                                                   unsigned short* __restrict__ vth,
                                                   unsigned short* __restrict__ vtl) {
  const int hh  = blockIdx.x;
  const int t0  = blockIdx.y << 6;
  const int tid = threadIdx.x;
  __shared__ unsigned short Th[64][40];
  __shared__ unsigned short Tl[64][40];
  const int lseq = tid >> 2, dg = (tid & 3) << 3;
  const size_t src = (size_t)(t0 + lseq) * TD3 + 2 * DMODEL + (hh << 5) + dg;
  *(short8*)&Th[lseq][dg] = *(const short8*)&qh[src];
  *(short8*)&Tl[lseq][dg] = *(const short8*)&ql[src];
  __syncthreads();
  const int d = tid >> 3, sg = (tid & 7) << 3;
  short8 oh, ol;
  #pragma unroll
  for (int j = 0; j < 8; ++j) { oh[j] = (short)Th[sg + j][d]; ol[j] = (short)Tl[sg + j][d]; }
  const size_t dst = ((size_t)(hh << 5) + d) * S_LEN + t0 + sg;
  *(short8*)&vth[dst] = oh;
  *(short8*)&vtl[dst] = ol;
}

// ---------------------------------------------------------------------------
// Split-K MFMA flash attention. Block = (head, 64 q-rows, kv-chunk).
// Each block covers half the q-tile's KV range; writes UNNORMALIZED partial
// O (fp32) + per-row (m, l) to workspace. exp2-domain softmax.
// Chunk sizes 8..16 tiles (vs 16..32 unsplit) -> 2x blocks, 2x balance.
// ---------------------------------------------------------------------------
__global__ __launch_bounds__(256) void attn_sk(const unsigned short* __restrict__ qh_g,
                                               const unsigned short* __restrict__ ql_g,
                                               const unsigned short* __restrict__ vth_g,
                                               const unsigned short* __restrict__ vtl_g,
                                               float* __restrict__ pO,
                                               float* __restrict__ pM,
                                               float* __restrict__ pL) {
  const int hh  = blockIdx.x;
  const int qt  = blockIdx.y;
  const int ck  = blockIdx.z;
  const int q0  = qt << 6;
  const int tid = threadIdx.x;
  const int w   = tid >> 6;
  const int lane = tid & 63;
  const int fr = lane & 15;
  const int fq = lane >> 4;
  constexpr float SCL2 = 0.17677669529663687f * 1.44269504088896341f;

  __shared__ __align__(16) unsigned short Kh[64][40];
  __shared__ __align__(16) unsigned short Kl[64][40];
  __shared__ __align__(16) unsigned short Vth[32][72];
  __shared__ __align__(16) unsigned short Vtl[32][72];
  __shared__ __align__(16) unsigned short Ph[4][16][72];
  __shared__ __align__(16) unsigned short Pl[4][16][72];

  const int qrow = q0 + (w << 4) + fr;
  const short8 fQh = *(const short8*)&qh_g[(size_t)qrow * TD3 + hh * HDIM + (fq << 3)];
  const short8 fQl = *(const short8*)&ql_g[(size_t)qrow * TD3 + hh * HDIM + (fq << 3)];

  float m = -3.0e38f, l = 0.f;
  f32x4 accO[2];
  accO[0] = (f32x4){0.f, 0.f, 0.f, 0.f};
  accO[1] = (f32x4){0.f, 0.f, 0.f, 0.f};

  const int nt_total = (qt < 16) ? 16 : (qt + 1);
  const int half     = nt_total >> 1;
  const int t_begin  = ck ? half : 0;
  const int t_end    = ck ? nt_total : half;

  const int krow = tid >> 2, kcol = (tid & 3) << 3;  // K staging
  const int vd = tid >> 3, vseg = tid & 7;           // V staging from Vt

  for (int t = t_begin; t < t_end; ++t) {
    const int c0 = t << 6;
    __syncthreads();
    *(short8*)&Kh[krow][kcol] =
        *(const short8*)&qh_g[(size_t)(c0 + krow) * TD3 + DMODEL + hh * HDIM + kcol];
    *(short8*)&Kl[krow][kcol] =
        *(const short8*)&ql_g[(size_t)(c0 + krow) * TD3 + DMODEL + hh * HDIM + kcol];
    const size_t vsrc = ((size_t)(hh << 5) + vd) * S_LEN + c0 + (vseg << 3);
    *(short8*)&Vth[vd][vseg << 3] = *(const short8*)&vth_g[vsrc];
    *(short8*)&Vtl[vd][vseg << 3] = *(const short8*)&vtl_g[vsrc];
    __syncthreads();

    // ---- S^T = K . Q^T (3-product split), 4 subtiles of 16 kv cols ----
    f32x4 s4[4];
    #pragma unroll
    for (int sub = 0; sub < 4; ++sub) {
      s4[sub] = (f32x4){0.f, 0.f, 0.f, 0.f};
      const short8 kh = *(const short8*)&Kh[(sub << 4) + fr][fq << 3];
      const short8 kl = *(const short8*)&Kl[(sub << 4) + fr][fq << 3];
      s4[sub] = __builtin_amdgcn_mfma_f32_16x16x32_bf16(kh, fQh, s4[sub], 0, 0, 0);
      s4[sub] = __builtin_amdgcn_mfma_f32_16x16x32_bf16(kh, fQl, s4[sub], 0, 0, 0);
      s4[sub] = __builtin_amdgcn_mfma_f32_16x16x32_bf16(kl, fQh, s4[sub], 0, 0, 0);
    }

    // ---- masked online softmax (exp2 domain; lane fr owns q-row fr) ----
    float sv[16];
    float tmax = -3.0e38f;
    #pragma unroll
    for (int sub = 0; sub < 4; ++sub)
      #pragma unroll
      for (int i = 0; i < 4; ++i) {
        const int k = c0 + (sub << 4) + (fq << 2) + i;
        const bool ok = (k < XLEN_C) | (k <= qrow);
        const float val = ok ? s4[sub][i] * SCL2 : -3.0e38f;
        sv[(sub << 2) + i] = val;
        tmax = fmaxf(tmax, val);
      }
    tmax = fmaxf(tmax, __shfl_xor(tmax, 16));
    tmax = fmaxf(tmax, __shfl_xor(tmax, 32));
    const float mnew  = fmaxf(m, tmax);
    const float alpha = exp2f(m - mnew);
    m = mnew;
    float psum = 0.f;
    unsigned short p_h[16], p_l[16];
    #pragma unroll
    for (int idx = 0; idx < 16; ++idx) {
      const float p = exp2f(sv[idx] - mnew);
      psum += p;
      split2(p, p_h[idx], p_l[idx]);
    }
    psum += __shfl_xor(psum, 16);
    psum += __shfl_xor(psum, 32);
    l = l * alpha + psum;

    #pragma unroll
    for (int sub = 0; sub < 4; ++sub) {
      ushort4 uh, ul;
      uh.x = p_h[(sub << 2) + 0]; uh.y = p_h[(sub << 2) + 1];
      uh.z = p_h[(sub << 2) + 2]; uh.w = p_h[(sub << 2) + 3];
      ul.x = p_l[(sub << 2) + 0]; ul.y = p_l[(sub << 2) + 1];
      ul.z = p_l[(sub << 2) + 2]; ul.w = p_l[(sub << 2) + 3];
      *(ushort4*)&Ph[w][fr][(sub << 4) + (fq << 2)] = uh;
      *(ushort4*)&Pl[w][fr][(sub << 4) + (fq << 2)] = ul;
    }

    const float a0 = __shfl(alpha, (fq << 2) + 0);
    const float a1 = __shfl(alpha, (fq << 2) + 1);
    const float a2 = __shfl(alpha, (fq << 2) + 2);
    const float a3 = __shfl(alpha, (fq << 2) + 3);
    #pragma unroll
    for (int df = 0; df < 2; ++df) {
      accO[df][0] *= a0; accO[df][1] *= a1;
      accO[df][2] *= a2; accO[df][3] *= a3;
    }

    // ---- O += P . V (3-product split) ----
    #pragma unroll
    for (int kh2 = 0; kh2 < 2; ++kh2) {
      const short8 pah = *(const short8*)&Ph[w][fr][(kh2 << 5) + (fq << 3)];
      const short8 pal = *(const short8*)&Pl[w][fr][(kh2 << 5) + (fq << 3)];
      #pragma unroll
      for (int df = 0; df < 2; ++df) {
        const short8 vbh = *(const short8*)&Vth[(df << 4) + fr][(kh2 << 5) + (fq << 3)];
        const short8 vbl = *(const short8*)&Vtl[(df << 4) + fr][(kh2 << 5) + (fq << 3)];
        accO[df] = __builtin_amdgcn_mfma_f32_16x16x32_bf16(pah, vbh, accO[df], 0, 0, 0);
        accO[df] = __builtin_amdgcn_mfma_f32_16x16x32_bf16(pal, vbh, accO[df], 0, 0, 0);
        accO[df] = __builtin_amdgcn_mfma_f32_16x16x32_bf16(pah, vbl, accO[df], 0, 0, 0);
      }
    }
  }

  // ---- write unnormalized partial: pO[pidx][row][d], pM/pL[pidx][row] ----
  const int pidx = (((hh << 5) + qt) << 1) + ck;
  float* po = pO + (size_t)pidx * (64 * 32);
  #pragma unroll
  for (int df = 0; df < 2; ++df)
    #pragma unroll
    for (int i = 0; i < 4; ++i)
      po[(size_t)((w << 4) + (fq << 2) + i) * 32 + (df << 4) + fr] = accO[df][i];
  if (fq == 0) {
    pM[pidx * 64 + (w << 4) + fr] = m;
    pL[pidx * 64 + (w << 4) + fr] = l;
  }
}

// ---------------------------------------------------------------------------
// Combine 2 split-K partials: O = (w0*O0 + w1*O1) / (w0*l0 + w1*l1),
// w_i = exp2(m_i - max(m0,m1)). Writes split bf16 pair.
// Block = (head, q-tile), 256 threads; thread = (row, 8-col group).
// ---------------------------------------------------------------------------
__global__ __launch_bounds__(256) void attn_combine(const float* __restrict__ pO,
                                                    const float* __restrict__ pM,
                                                    const float* __restrict__ pL,
                                                    unsigned short* __restrict__ oh_g,
                                                    unsigned short* __restrict__ ol_g) {
  const int hh = blockIdx.x, qt = blockIdx.y;
  const int tid = threadIdx.x;
  const int row = tid >> 2;
  const int cg  = (tid & 3) << 3;
  const int b0  = (((hh << 5) + qt) << 1);
  const float m0 = pM[b0 * 64 + row], m1 = pM[(b0 + 1) * 64 + row];
  const float l0 = pL[b0 * 64 + row], l1 = pL[(b0 + 1) * 64 + row];
  const float M  = fmaxf(m0, m1);
  const float w0 = exp2f(m0 - M), w1 = exp2f(m1 - M);
  const float inv = 1.f / (w0 * l0 + w1 * l1);
  const float* o0 = pO + (size_t)b0 * 2048 + row * 32 + cg;
  const float* o1 = pO + (size_t)(b0 + 1) * 2048 + row * 32 + cg;
  short8 hs, ls;
  #pragma unroll
  for (int j = 0; j < 8; ++j) {
    const float v = (w0 * o0[j] + w1 * o1[j]) * inv;
    unsigned short h, lo; split2(v, h, lo);
    hs[j] = (short)h; ls[j] = (short)lo;
  }
  const size_t dst = (size_t)((qt << 6) + row) * DMODEL + (hh << 5) + cg;
  *(short8*)&oh_g[dst] = hs;
  *(short8*)&ol_g[dst] = ls;
}

// ---------------------------------------------------------------------------
// Fused residual add + LayerNorm; emits fp32 AND bf16 hi/lo pair.
// ---------------------------------------------------------------------------
__global__ __launch_bounds__(256) void add_layernorm(const float* __restrict__ h,
                                                     const float* __restrict__ r,
                                                     const float* __restrict__ w,
                                                     const float* __restrict__ b,
                                                     float* __restrict__ out,
                                                     unsigned short* __restrict__ oh,
                                                     unsigned short* __restrict__ ol) {
  const int row = blockIdx.x;
  const int tid = threadIdx.x;
  const float2 hv = *(const float2*)&h[(size_t)row * DMODEL + tid * 2];
  const float2 rv = *(const float2*)&r[(size_t)row * DMODEL + tid * 2];
  const float a0 = hv.x + rv.x, a1 = hv.y + rv.y;
  float s = a0 + a1, ss = a0 * a0 + a1 * a1;
  #pragma unroll
  for (int off = 32; off; off >>= 1) {
    s  += __shfl_xor(s, off);
    ss += __shfl_xor(ss, off);
  }
  __shared__ float sb[4], ssb[4];
  const int wid = tid >> 6;
  if ((tid & 63) == 0) { sb[wid] = s; ssb[wid] = ss; }
  __syncthreads();
  s  = sb[0] + sb[1] + sb[2] + sb[3];
  ss = ssb[0] + ssb[1] + ssb[2] + ssb[3];
  const float mean = s * (1.f / DMODEL);
  const float var  = ss * (1.f / DMODEL) - mean * mean;
  const float rs   = rsqrtf(var + 1e-5f);
  const float2 wv = *(const float2*)&w[tid * 2];
  const float2 bv = *(const float2*)&b[tid * 2];
  const float o0 = (a0 - mean) * rs * wv.x + bv.x;
  const float o1 = (a1 - mean) * rs * wv.y + bv.y;
  float2 o; o.x = o0; o.y = o1;
  *(float2*)&out[(size_t)row * DMODEL + tid * 2] = o;
  unsigned short h0, l0, h1, l1;
  split2(o0, h0, l0); split2(o1, h1, l1);
  ushort2 uh; uh.x = h0; uh.y = h1;
  ushort2 ul; ul.x = l0; ul.y = l1;
  *(ushort2*)&oh[(size_t)row * DMODEL + tid * 2] = uh;
  *(ushort2*)&ol[(size_t)row * DMODEL + tid * 2] = ul;
}

// ---------------------------------------------------------------------------
__global__ __launch_bounds__(256) void split_w(const float* __restrict__ src,
                                               unsigned short* __restrict__ h,
                                               unsigned short* __restrict__ l) {
  const int i = blockIdx.x * 256 + threadIdx.x;
  const float4 v = *(const float4*)&src[(size_t)i * 4];
  const float vf[4] = {v.x, v.y, v.z, v.w};
  ushort4 uh, ul;
  unsigned short hh, ll;
  split2(vf[0], hh, ll); uh.x = hh; ul.x = ll;
  split2(vf[1], hh, ll); uh.y = hh; ul.y = ll;
  split2(vf[2], hh, ll); uh.z = hh; ul.z = ll;
  split2(vf[3], hh, ll); uh.w = hh; ul.w = ll;
  *(ushort4*)&h[(size_t)i * 4] = uh;
  *(ushort4*)&l[(size_t)i * 4] = ul;
}

__global__ __launch_bounds__(256) void split_init(const float* __restrict__ x,
                                                  float* __restrict__ f,
                                                  unsigned short* __restrict__ h,
                                                  unsigned short* __restrict__ l,
                                                  int n4) {
  const int i = blockIdx.x * 256 + threadIdx.x;
  if (i >= n4) return;
  const float4 v = *(const float4*)&x[(size_t)i * 4];
  *(float4*)&f[(size_t)i * 4] = v;
  const float vf[4] = {v.x, v.y, v.z, v.w};
  ushort4 uh, ul;
  unsigned short hh, ll;
  split2(vf[0], hh, ll); uh.x = hh; ul.x = ll;
  split2(vf[1], hh, ll); uh.y = hh; ul.y = ll;
  split2(vf[2], hh, ll); uh.z = hh; ul.z = ll;
  split2(vf[3], hh, ll); uh.w = hh; ul.w = ll;
  *(ushort4*)&h[(size_t)i * 4] = uh;
  *(ushort4*)&l[(size_t)i * 4] = ul;
}

// ---------------------------------------------------------------------------
extern "C" void kernel_launch(void* const* d_in, const int* in_sizes, int n_in,
                              void* d_out, int out_size, void* d_ws, size_t ws_size,
                              hipStream_t stream) {
  const float* x     = (const float*)d_in[0];
  const float* qkv_w = (const float*)d_in[1];
  const float* qkv_b = (const float*)d_in[2];
  const float* out_w = (const float*)d_in[3];
  const float* out_b = (const float*)d_in[4];
  const float* w1    = (const float*)d_in[5];
  const float* b1    = (const float*)d_in[6];
  const float* w2    = (const float*)d_in[7];
  const float* b2    = (const float*)d_in[8];
  const float* nw1   = (const float*)d_in[9];
  const float* nb1   = (const float*)d_in[10];
  const float* nw2   = (const float*)d_in[11];
  const float* nb2   = (const float*)d_in[12];

  // ---- workspace layout ----
  char* p = (char*)d_ws;
  float* Hc = (float*)p;                     p += (size_t)S_LEN * DMODEL * 4;
  unsigned short* Hh = (unsigned short*)p;   p += (size_t)S_LEN * DMODEL * 2;
  unsigned short* Hl = (unsigned short*)p;   p += (size_t)S_LEN * DMODEL * 2;
  unsigned short* qkvh = (unsigned short*)p; p += (size_t)S_LEN * TD3 * 2;
  unsigned short* qkvl = (unsigned short*)p; p += (size_t)S_LEN * TD3 * 2;
  unsigned short* oath = (unsigned short*)p; p += (size_t)S_LEN * DMODEL * 2;
  unsigned short* oatl = (unsigned short*)p; p += (size_t)S_LEN * DMODEL * 2;
  float* opr = (float*)p;                    p += (size_t)S_LEN * DMODEL * 4;
  unsigned short* midh = (unsigned short*)p; p += (size_t)S_LEN * FFDIM * 2;
  unsigned short* midl = (unsigned short*)p; p += (size_t)S_LEN * FFDIM * 2;
  unsigned short* vth = (unsigned short*)p;  p += (size_t)S_LEN * DMODEL * 2;
  unsigned short* vtl = (unsigned short*)p;  p += (size_t)S_LEN * DMODEL * 2;
  float* pO = (float*)p;                     p += (size_t)NHEAD * NQT * 2 * 64 * 32 * 4;
  float* pM = (float*)p;                     p += (size_t)NHEAD * NQT * 2 * 64 * 4;
  float* pL = (float*)p;                     p += (size_t)NHEAD * NQT * 2 * 64 * 4;
  // pre-split weights (288 MB) — only if ws is big enough
  unsigned short* qkvWh = (unsigned short*)p; p += (size_t)NLAYER * TD3 * DMODEL * 2;
  unsigned short* qkvWl = (unsigned short*)p; p += (size_t)NLAYER * TD3 * DMODEL * 2;
  unsigned short* outWh = (unsigned short*)p; p += (size_t)NLAYER * DMODEL * DMODEL * 2;
  unsigned short* outWl = (unsigned short*)p; p += (size_t)NLAYER * DMODEL * DMODEL * 2;
  unsigned short* w1h = (unsigned short*)p;   p += (size_t)NLAYER * FFDIM * DMODEL * 2;
  unsigned short* w1l = (unsigned short*)p;   p += (size_t)NLAYER * FFDIM * DMODEL * 2;
  unsigned short* w2h = (unsigned short*)p;   p += (size_t)NLAYER * DMODEL * FFDIM * 2;
  unsigned short* w2l = (unsigned short*)p;   p += (size_t)NLAYER * DMODEL * FFDIM * 2;
  const size_t need = (size_t)(p - (char*)d_ws);
  const bool presplit = ws_size >= need;

  split_init<<<(S_LEN * DMODEL / 4 + 255) / 256, 256, 0, stream>>>(
      x, Hc, Hh, Hl, S_LEN * DMODEL / 4);

  if (presplit) {
    split_w<<<NLAYER * TD3 * DMODEL / 1024, 256, 0, stream>>>(qkv_w, qkvWh, qkvWl);
    split_w<<<NLAYER * DMODEL * DMODEL / 1024, 256, 0, stream>>>(out_w, outWh, outWl);
    split_w<<<NLAYER * FFDIM * DMODEL / 1024, 256, 0, stream>>>(w1, w1h, w1l);
    split_w<<<NLAYER * DMODEL * FFDIM / 1024, 256, 0, stream>>>(w2, w2h, w2l);
  }

  for (int l = 0; l < NLAYER; ++l) {
    const float* qw = qkv_w + (size_t)l * TD3 * DMODEL;
    const float* qb = qkv_b + (size_t)l * TD3;
    const float* ow = out_w + (size_t)l * DMODEL * DMODEL;
    const float* ob = out_b + (size_t)l * DMODEL;
    const float* W1 = w1 + (size_t)l * FFDIM * DMODEL;
    const float* B1 = b1 + (size_t)l * FFDIM;
    const float* W2 = w2 + (size_t)l * DMODEL * FFDIM;
    const float* B2 = b2 + (size_t)l * DMODEL;

    if (presplit) {
      const unsigned short* qwh = qkvWh + (size_t)l * TD3 * DMODEL;
      const unsigned short* qwl = qkvWl + (size_t)l * TD3 * DMODEL;
      const unsigned short* owh = outWh + (size_t)l * DMODEL * DMODEL;
      const unsigned short* owl = outWl + (size_t)l * DMODEL * DMODEL;
      const unsigned short* W1h = w1h + (size_t)l * FFDIM * DMODEL;
      const unsigned short* W1l = w1l + (size_t)l * FFDIM * DMODEL;
      const unsigned short* W2h = w2h + (size_t)l * DMODEL * FFDIM;
      const unsigned short* W2l = w2l + (size_t)l * DMODEL * FFDIM;

      gemm_mfma<4, false, true, true><<<dim3(TD3 / 64, S_LEN / 128), 256, 0, stream>>>(
          Hh, Hl, nullptr, qwh, qwl, qb, nullptr, qkvh, qkvl, TD3, DMODEL);
      transpose_v<<<dim3(NHEAD, S_LEN / 64), 256, 0, stream>>>(qkvh, qkvl, vth, vtl);
      attn_sk<<<dim3(NHEAD, NQT, 2), 256, 0, stream>>>(qkvh, qkvl, vth, vtl, pO, pM, pL);
      attn_combine<<<dim3(NHEAD, NQT), 256, 0, stream>>>(pO, pM, pL, oath, oatl);
      gemm_mfma<2, false, false, true><<<dim3(DMODEL / 64, S_LEN / 64), 256, 0, stream>>>(
          oath, oatl, nullptr, owh, owl, ob, opr, nullptr, nullptr, DMODEL, DMODEL);
      add_layernorm<<<S_LEN, 256, 0, stream>>>(
          Hc, opr, nw1 + (size_t)l * DMODEL, nb1 + (size_t)l * DMODEL, Hc, Hh, Hl);
      gemm_mfma<4, true, true, true><<<dim3(FFDIM / 64, S_LEN / 128), 256, 0, stream>>>(
          Hh, Hl, nullptr, W1h, W1l, B1, nullptr, midh, midl, FFDIM, DMODEL);
      gemm_mfma<2, false, false, true><<<dim3(DMODEL / 64, S_LEN / 64), 256, 0, stream>>>(
          midh, midl, nullptr, W2h, W2l, B2, opr, nullptr, nullptr, DMODEL, FFDIM);
      add_layernorm<<<S_LEN, 256, 0, stream>>>(
          Hc, opr, nw2 + (size_t)l * DMODEL, nb2 + (size_t)l * DMODEL, Hc, Hh, Hl);
    } else {
      gemm_mfma<4, false, true, false><<<dim3(TD3 / 64, S_LEN / 128), 256, 0, stream>>>(
          Hh, Hl, qw, nullptr, nullptr, qb, nullptr, qkvh, qkvl, TD3, DMODEL);
      transpose_v<<<dim3(NHEAD, S_LEN / 64), 256, 0, stream>>>(qkvh, qkvl, vth, vtl);
      attn_sk<<<dim3(NHEAD, NQT, 2), 256, 0, stream>>>(qkvh, qkvl, vth, vtl, pO, pM, pL);
      attn_combine<<<dim3(NHEAD, NQT), 256, 0, stream>>>(pO, pM, pL, oath, oatl);
      gemm_mfma<2, false, false, false><<<dim3(DMODEL / 64, S_LEN / 64), 256, 0, stream>>>(
          oath, oatl, ow, nullptr, nullptr, ob, opr, nullptr, nullptr, DMODEL, DMODEL);
      add_layernorm<<<S_LEN, 256, 0, stream>>>(
          Hc, opr, nw1 + (size_t)l * DMODEL, nb1 + (size_t)l * DMODEL, Hc, Hh, Hl);
      gemm_mfma<4, true, true, false><<<dim3(FFDIM / 64, S_LEN / 128), 256, 0, stream>>>(
          Hh, Hl, W1, nullptr, nullptr, B1, nullptr, midh, midl, FFDIM, DMODEL);
      gemm_mfma<2, false, false, false><<<dim3(DMODEL / 64, S_LEN / 64), 256, 0, stream>>>(
          midh, midl, W2, nullptr, nullptr, B2, opr, nullptr, nullptr, DMODEL, FFDIM);
      add_layernorm<<<S_LEN, 256, 0, stream>>>(
          Hc, opr, nw2 + (size_t)l * DMODEL, nb2 + (size_t)l * DMODEL, Hc, Hh, Hl);
    }
  }

  hipMemcpyAsync(d_out, Hc, sizeof(float) * S_LEN * DMODEL,
                 hipMemcpyDeviceToDevice, stream);
}